// Round 2
// baseline (5563.859 us; speedup 1.0000x reference)
//
#include <hip/hip_runtime.h>
#include <hip/hip_bf16.h>
#include <math.h>

#define Bn 16
#define Sn 512
#define Nn 321
#define Dn 512
#define DFn 2048
#define Pn 96

static __device__ __forceinline__ float gelu_exact(float x) {
    return 0.5f * x * (1.0f + erff(x * 0.7071067811865476f));
}

// ---------- per-(b,n) mean/std over S ----------
__global__ void stats_kernel(const float* __restrict__ x, float* __restrict__ means,
                             float* __restrict__ stdev) {
    int b = blockIdx.y;
    int n = blockIdx.x * 256 + threadIdx.x;
    if (n >= Nn) return;
    const float* p = x + (size_t)b * Sn * Nn + n;
    float s = 0.f, s2 = 0.f;
    for (int ss = 0; ss < Sn; ++ss) { float v = p[(size_t)ss * Nn]; s += v; s2 += v * v; }
    float mu = s * (1.0f / Sn);
    float var = s2 * (1.0f / Sn) - mu * mu;
    means[b * Nn + n] = mu;
    stdev[b * Nn + n] = sqrtf(var + 1e-5f);
}

// ---------- xT[b,n,s] = (x[b,s,n]-mu)/sd ----------
__global__ void transpose_norm_kernel(const float* __restrict__ x,
                                      const float* __restrict__ means,
                                      const float* __restrict__ stdev,
                                      float* __restrict__ xT) {
    __shared__ float tile[32][33];
    int b = blockIdx.z;
    int s0 = blockIdx.x * 32, n0 = blockIdx.y * 32;
    int tx = threadIdx.x, ty = threadIdx.y; // 32 x 8
#pragma unroll
    for (int u = 0; u < 4; ++u) {
        int srow = ty + u * 8;
        int n = n0 + tx;
        tile[srow][tx] = (n < Nn) ? x[((size_t)b * Sn + (s0 + srow)) * Nn + n] : 0.f;
    }
    __syncthreads();
#pragma unroll
    for (int u = 0; u < 4; ++u) {
        int n = n0 + ty + u * 8;
        int s = s0 + tx;
        if (n < Nn) {
            float mu = means[b * Nn + n], sd = stdev[b * Nn + n];
            xT[((size_t)b * Nn + n) * Sn + s] = (tile[tx][ty + u * 8] - mu) / sd;
        }
    }
}

// ---------- tiled fp32 GEMM ----------
// C[i,j] = sum_k opA(i,k)*opB(j,k) (+bias[j]) (+gelu)
// AT=false: A[i*lda+k]   AT=true: A[k*lda+i]
// BT=true:  B[j*ldb+k]   BT=false: B[k*ldb+j]
// batch z: zi=z%innerB, zo=z/innerB; base += zi*s?i + zo*s?o
template <bool AT, bool BT, int EPI>
__global__ __launch_bounds__(256) void gemm_kernel(
    const float* __restrict__ A, const float* __restrict__ Bm,
    const float* __restrict__ bias, float* __restrict__ C,
    int Mdim, int Ndim, int Kdim, int lda, int ldb, int ldc,
    long sAi, long sAo, long sBi, long sBo, long sCi, long sCo, int innerB) {
    int z = blockIdx.z;
    int zi = z % innerB, zo = z / innerB;
    const float* Ab = A + (size_t)zi * sAi + (size_t)zo * sAo;
    const float* Bb = Bm + (size_t)zi * sBi + (size_t)zo * sBo;
    float* Cb = C + (size_t)zi * sCi + (size_t)zo * sCo;
    __shared__ float As[16][64];
    __shared__ float Bs[16][64];
    int t = threadIdx.x;
    int i0 = blockIdx.y * 64, j0 = blockIdx.x * 64;
    int tx = t & 15, ty = t >> 4;
    float acc[4][4] = {{0.f}};
    for (int k0 = 0; k0 < Kdim; k0 += 16) {
        if (!AT) {
            int ii = t >> 2, kk = (t & 3) * 4;
            int gi = i0 + ii;
#pragma unroll
            for (int u = 0; u < 4; ++u) {
                int gk = k0 + kk + u;
                As[kk + u][ii] = (gi < Mdim && gk < Kdim) ? Ab[(size_t)gi * lda + gk] : 0.f;
            }
        } else {
            int ii = t & 63, kkb = (t >> 6) * 4;
            int gi = i0 + ii;
#pragma unroll
            for (int u = 0; u < 4; ++u) {
                int gk = k0 + kkb + u;
                As[kkb + u][ii] = (gi < Mdim && gk < Kdim) ? Ab[(size_t)gk * lda + gi] : 0.f;
            }
        }
        if (BT) {
            int jj = t >> 2, kk = (t & 3) * 4;
            int gj = j0 + jj;
#pragma unroll
            for (int u = 0; u < 4; ++u) {
                int gk = k0 + kk + u;
                Bs[kk + u][jj] = (gj < Ndim && gk < Kdim) ? Bb[(size_t)gj * ldb + gk] : 0.f;
            }
        } else {
            int jj = t & 63, kkb = (t >> 6) * 4;
            int gj = j0 + jj;
#pragma unroll
            for (int u = 0; u < 4; ++u) {
                int gk = k0 + kkb + u;
                Bs[kkb + u][jj] = (gj < Ndim && gk < Kdim) ? Bb[(size_t)gk * ldb + gj] : 0.f;
            }
        }
        __syncthreads();
#pragma unroll
        for (int k = 0; k < 16; ++k) {
            float4 a4 = *reinterpret_cast<const float4*>(&As[k][ty * 4]);
            float4 b4 = *reinterpret_cast<const float4*>(&Bs[k][tx * 4]);
            float ar[4] = {a4.x, a4.y, a4.z, a4.w};
            float br[4] = {b4.x, b4.y, b4.z, b4.w};
#pragma unroll
            for (int ii = 0; ii < 4; ++ii)
#pragma unroll
                for (int jj = 0; jj < 4; ++jj) acc[ii][jj] += ar[ii] * br[jj];
        }
        __syncthreads();
    }
#pragma unroll
    for (int ii = 0; ii < 4; ++ii) {
        int gi = i0 + ty * 4 + ii;
        if (gi >= Mdim) continue;
#pragma unroll
        for (int jj = 0; jj < 4; ++jj) {
            int gj = j0 + tx * 4 + jj;
            if (gj >= Ndim) continue;
            float v = acc[ii][jj];
            if (bias) v += bias[gj];
            if (EPI == 1) v = gelu_exact(v);
            Cb[(size_t)gi * ldc + gj] = v;
        }
    }
}

// ---------- SWT decomposition: h(b,n,:) -> coeffs(b,n,4,:) ----------
__global__ __launch_bounds__(128) void swt_dec_kernel(
    const float* __restrict__ h, const float* __restrict__ h0f,
    const float* __restrict__ h1f, float* __restrict__ coeffs) {
    __shared__ float a[2][512];
    int b = blockIdx.y, n = blockIdx.x, t = threadIdx.x;
    const float* hrow = h + ((size_t)b * Nn + n) * Dn;
#pragma unroll
    for (int u = 0; u < 4; ++u) a[0][t + u * 128] = hrow[t + u * 128];
    float f0[3], f1[3];
#pragma unroll
    for (int k = 0; k < 3; ++k) { f0[k] = h0f[n * 3 + k]; f1[k] = h1f[n * 3 + k]; }
    __syncthreads();
    float* cb = coeffs + ((size_t)b * Nn + n) * 4 * Dn;
    int cur = 0;
    for (int lev = 0; lev < 3; ++lev) {
        int dil = 1 << lev;
        int pl = 2 * dil - (3 * dil) / 2; // 1,1,2
#pragma unroll
        for (int u = 0; u < 4; ++u) {
            int d = t + u * 128;
            float dv = 0.f, av = 0.f;
#pragma unroll
            for (int k = 0; k < 3; ++k) {
                int idx = (d + k * dil - pl) & 511;
                float xv = a[cur][idx];
                dv += f1[k] * xv;
                av += f0[k] * xv;
            }
            cb[(size_t)(3 - lev) * Dn + d] = dv;
            a[cur ^ 1][d] = av;
        }
        __syncthreads();
        cur ^= 1;
    }
#pragma unroll
    for (int u = 0; u < 4; ++u) cb[t + u * 128] = a[cur][t + u * 128];
}

// ---------- SWT reconstruction: attn(b,m,n,:) -> rec(b,n,:) ----------
__global__ __launch_bounds__(128) void swt_rec_kernel(
    const float* __restrict__ attn, const float* __restrict__ g0f,
    const float* __restrict__ g1f, float* __restrict__ rec) {
    __shared__ float a[2][512];
    __shared__ float det[512];
    int b = blockIdx.y, n = blockIdx.x, t = threadIdx.x;
    const float* base = attn + ((size_t)(b * 4) * Nn + n) * Dn; // m stride = Nn*Dn
#pragma unroll
    for (int u = 0; u < 4; ++u) a[0][t + u * 128] = base[t + u * 128];
    float w0[3], w1[3];
#pragma unroll
    for (int k = 0; k < 3; ++k) { w0[k] = g0f[n * 3 + k]; w1[k] = g1f[n * 3 + k]; }
    int cur = 0;
    for (int i = 0; i < 3; ++i) {
        int dil = 4 >> i;
        int pl = (3 * dil) / 2; // 6,3,1
        const float* drow = base + (size_t)(1 + i) * Nn * Dn;
#pragma unroll
        for (int u = 0; u < 4; ++u) det[t + u * 128] = drow[t + u * 128];
        __syncthreads();
#pragma unroll
        for (int u = 0; u < 4; ++u) {
            int d = t + u * 128;
            float s = 0.f;
#pragma unroll
            for (int k = 0; k < 3; ++k) {
                int idx = (d + k * dil - pl) & 511;
                s += w0[k] * a[cur][idx] + w1[k] * det[idx];
            }
            a[cur ^ 1][d] = s * 0.5f;
        }
        __syncthreads();
        cur ^= 1;
    }
    float* out = rec + ((size_t)b * Nn + n) * Dn;
#pragma unroll
    for (int u = 0; u < 4; ++u) out[t + u * 128] = a[cur][t + u * 128];
}

// ---------- column sum of squares: qn2[bm,e] = sum_n Q0[(b,n,m),e]^2 ----------
__global__ __launch_bounds__(256) void colsq_kernel(const float* __restrict__ Q0,
                                                    float* __restrict__ outv) {
    int bm = blockIdx.y;
    int b = bm >> 2, m = bm & 3;
    int e0 = blockIdx.x * 64;
    int tx = threadIdx.x & 63, ty = threadIdx.x >> 6;
    const float* base = Q0 + ((size_t)b * Nn * 4 + m) * 512;
    float s = 0.f;
    for (int n = ty; n < Nn; n += 4) {
        float v = base[(size_t)n * 2048 + e0 + tx];
        s += v * v;
    }
    __shared__ float red[4][64];
    red[ty][tx] = s;
    __syncthreads();
    if (ty == 0)
        outv[(size_t)bm * 512 + e0 + tx] = red[0][tx] + red[1][tx] + red[2][tx] + red[3][tx];
}

// ---------- geometric scores + softmax, in place on Smat[bm_local,l,s] ----------
__global__ __launch_bounds__(256) void wedge_softmax_kernel(
    float* __restrict__ Smat, const float* __restrict__ qn2, const float* __restrict__ kn2) {
    int bm = blockIdx.y, l = blockIdx.x, t = threadIdx.x;
    float* row = Smat + ((size_t)bm * 512 + l) * 512;
    const float* kn = kn2 + (size_t)bm * 512;
    float q2 = qn2[(size_t)bm * 512 + l];
    const float scale = rsqrtf(321.0f);
    float v[2];
    float mx = -1e30f;
#pragma unroll
    for (int u = 0; u < 2; ++u) {
        int s = t + u * 256;
        float d = row[s];
        float w = sqrtf(fmaxf(q2 * kn[s] - d * d, 0.f) + 1e-8f);
        float sc = (0.7f * d + 0.3f * w) * scale;
        v[u] = sc;
        mx = fmaxf(mx, sc);
    }
    __shared__ float red[256];
    red[t] = mx;
    __syncthreads();
    for (int o = 128; o > 0; o >>= 1) {
        if (t < o) red[t] = fmaxf(red[t], red[t + o]);
        __syncthreads();
    }
    mx = red[0];
    __syncthreads();
    float sum = 0.f;
#pragma unroll
    for (int u = 0; u < 2; ++u) {
        v[u] = expf(v[u] - mx);
        sum += v[u];
    }
    red[t] = sum;
    __syncthreads();
    for (int o = 128; o > 0; o >>= 1) {
        if (t < o) red[t] += red[t + o];
        __syncthreads();
    }
    float inv = 1.0f / red[0];
#pragma unroll
    for (int u = 0; u < 2; ++u) row[t + u * 256] = v[u] * inv;
}

// ---------- LayerNorm over D of (A [+ R]) ----------
__global__ __launch_bounds__(128) void ln_kernel(
    const float* __restrict__ A, const float* __restrict__ R,
    const float* __restrict__ g, const float* __restrict__ bb, float* __restrict__ out) {
    size_t r = blockIdx.x;
    int t = threadIdx.x;
    const float* ra = A + r * Dn;
    float x[4];
    float s = 0.f, s2 = 0.f;
#pragma unroll
    for (int u = 0; u < 4; ++u) {
        int d = t + u * 128;
        float v = ra[d];
        if (R) v += R[r * Dn + d];
        x[u] = v;
        s += v;
        s2 += v * v;
    }
    __shared__ float rs[128], rs2[128];
    rs[t] = s;
    rs2[t] = s2;
    __syncthreads();
    for (int o = 64; o > 0; o >>= 1) {
        if (t < o) { rs[t] += rs[t + o]; rs2[t] += rs2[t + o]; }
        __syncthreads();
    }
    float mean = rs[0] * (1.0f / Dn);
    float var = rs2[0] * (1.0f / Dn) - mean * mean;
    float inv = rsqrtf(var + 1e-5f);
#pragma unroll
    for (int u = 0; u < 4; ++u) {
        int d = t + u * 128;
        out[r * Dn + d] = (x[u] - mean) * inv * g[d] + bb[d];
    }
}

// ---------- dec[b,p,n] = ptmp[(b,n),p]*sd[b,n] + mu[b,n] ----------
__global__ void out_scale_kernel(const float* __restrict__ ptmp,
                                 const float* __restrict__ means,
                                 const float* __restrict__ stdev, float* __restrict__ dec) {
    int idx = blockIdx.x * 256 + threadIdx.x;
    if (idx >= Bn * Pn * Nn) return;
    int n = idx % Nn;
    int bp = idx / Nn;
    int p = bp % Pn;
    int b = bp / Pn;
    float v = ptmp[((size_t)b * Nn + n) * Pn + p];
    dec[idx] = v * stdev[b * Nn + n] + means[b * Nn + n];
}

extern "C" void kernel_launch(void* const* d_in, const int* in_sizes, int n_in,
                              void* d_out, int out_size, void* d_ws, size_t ws_size,
                              hipStream_t stream) {
    const float* x_enc = (const float*)d_in[0];
    const float* emb_W = (const float*)d_in[1];
    const float* emb_b = (const float*)d_in[2];
    const float* h0 = (const float*)d_in[3];
    const float* h1 = (const float*)d_in[4];
    const float* g0 = (const float*)d_in[5];
    const float* g1 = (const float*)d_in[6];
    const float* Wq = (const float*)d_in[7];
    const float* bq = (const float*)d_in[8];
    const float* Wk = (const float*)d_in[9];
    const float* bk = (const float*)d_in[10];
    const float* Wv = (const float*)d_in[11];
    const float* bv = (const float*)d_in[12];
    const float* Wo = (const float*)d_in[13];
    const float* bo = (const float*)d_in[14];
    const float* W1 = (const float*)d_in[15];
    const float* b1 = (const float*)d_in[16];
    const float* W2 = (const float*)d_in[17];
    const float* b2 = (const float*)d_in[18];
    const float* ln1_g = (const float*)d_in[19];
    const float* ln1_b = (const float*)d_in[20];
    const float* ln2_g = (const float*)d_in[21];
    const float* ln2_b = (const float*)d_in[22];
    const float* lnf_g = (const float*)d_in[23];
    const float* lnf_b = (const float*)d_in[24];
    const float* proj_W = (const float*)d_in[25];
    const float* proj_b = (const float*)d_in[26];

    float* dec = (float*)d_out;
    float* means = dec + (size_t)Bn * Pn * Nn;
    float* stdev = means + (size_t)Bn * Nn;

    // ---- workspace layout (total 44,769,280 floats = 179.1 MB) ----
    // A: hbuf      2,629,632
    // B: big0     10,518,528  (xT | coeffs | Smat(first 4,194,304) | y)
    // C: Q0/attn  10,518,528  (Q0, then attn per-chunk, then ptmp)
    // D: K0       10,518,528  (K0, then rec/x1/tmp)
    // E: V0       10,518,528
    // F,G: qn2,kn2    65,536
    float* ws = (float*)d_ws;
    size_t o = 0;
    float* hbuf = ws + o; o += (size_t)Bn * Nn * Dn;
    float* big0 = ws + o; o += (size_t)Bn * Nn * 4 * Dn;
    float* QA = ws + o;   o += (size_t)Bn * Nn * 4 * Dn;
    float* K0 = ws + o;   o += (size_t)Bn * Nn * 4 * Dn;
    float* V0 = ws + o;   o += (size_t)Bn * Nn * 4 * Dn;
    float* qn2 = ws + o;  o += (size_t)64 * 512;
    float* kn2 = ws + o;  o += (size_t)64 * 512;

    float* xT = big0;                       // dead before coeffs written
    float* Smat = big0;                     // 16*512*512 = 4,194,304 floats (chunked)
    float* rec = K0;                        // after K0 dead
    float* x1 = K0 + (size_t)Bn * Nn * Dn;
    float* tmp = K0 + (size_t)2 * Bn * Nn * Dn;
    float* ptmp = QA;                       // after attn dead

    const int R = Bn * Nn;   // 5136
    const int RQ = R * 4;    // 20544
    const long sbm = (long)4 * Nn * 512;   // per-b stride in QA/K0/V0
    const long sS = (long)512 * 512;

    stats_kernel<<<dim3((Nn + 255) / 256, Bn), 256, 0, stream>>>(x_enc, means, stdev);
    transpose_norm_kernel<<<dim3(Sn / 32, (Nn + 31) / 32, Bn), dim3(32, 8), 0, stream>>>(
        x_enc, means, stdev, xT);

    // h = xT(5136x512) * emb_W(512x512)^T + emb_b
    gemm_kernel<false, true, 0><<<dim3(Dn / 64, (R + 63) / 64, 1), 256, 0, stream>>>(
        xT, emb_W, emb_b, hbuf, R, Dn, Sn, Sn, Sn, Dn, 0, 0, 0, 0, 0, 0, 1);

    for (int l = 0; l < 2; ++l) {
        const float* h0l = h0 + (size_t)l * Nn * 3;
        const float* h1l = h1 + (size_t)l * Nn * 3;
        const float* g0l = g0 + (size_t)l * Nn * 3;
        const float* g1l = g1 + (size_t)l * Nn * 3;

        swt_dec_kernel<<<dim3(Nn, Bn), 128, 0, stream>>>(hbuf, h0l, h1l, big0);

        // QKV projections: rows (b,n,m), K=D; output layout (b,n,m,e)
        gemm_kernel<false, true, 0><<<dim3(Dn / 64, RQ / 64, 1), 256, 0, stream>>>(
            big0, Wq + (size_t)l * Dn * Dn, bq + (size_t)l * Dn, QA,
            RQ, Dn, Dn, Dn, Dn, Dn, 0, 0, 0, 0, 0, 0, 1);
        gemm_kernel<false, true, 0><<<dim3(Dn / 64, RQ / 64, 1), 256, 0, stream>>>(
            big0, Wk + (size_t)l * Dn * Dn, bk + (size_t)l * Dn, K0,
            RQ, Dn, Dn, Dn, Dn, Dn, 0, 0, 0, 0, 0, 0, 1);
        gemm_kernel<false, true, 0><<<dim3(Dn / 64, RQ / 64, 1), 256, 0, stream>>>(
            big0, Wv + (size_t)l * Dn * Dn, bv + (size_t)l * Dn, V0,
            RQ, Dn, Dn, Dn, Dn, Dn, 0, 0, 0, 0, 0, 0, 1);

        colsq_kernel<<<dim3(8, 64), 256, 0, stream>>>(QA, qn2);
        colsq_kernel<<<dim3(8, 64), 256, 0, stream>>>(K0, kn2);

        // attention in 4 chunks of 4 batches (16 bm each); Smat aliases big0
        // (coeffs dead after QKV); attn chunk writes overwrite QA's chunk-g
        // region only after dot(g) consumed it.
        for (int g = 0; g < 4; ++g) {
            const float* Qc = QA + (size_t)4 * g * sbm;
            const float* Kc = K0 + (size_t)4 * g * sbm;
            const float* Vc = V0 + (size_t)4 * g * sbm;
            float* attc = QA + (size_t)4 * g * sbm;

            // dot[bm_local,l,s] = sum_n Qc[(b',n,m),l]*Kc[(b',n,m),s]
            gemm_kernel<true, false, 0><<<dim3(8, 8, 16), 256, 0, stream>>>(
                Qc, Kc, nullptr, Smat, 512, 512, Nn, 2048, 2048, 512,
                512, sbm, 512, sbm, sS, 4 * sS, 4);

            wedge_softmax_kernel<<<dim3(512, 16), 256, 0, stream>>>(
                Smat, qn2 + (size_t)16 * g * 512, kn2 + (size_t)16 * g * 512);

            // attn[b',m,n,l] = sum_s Vc[(b',n,m),s] * Smat[bm_local,l,s]
            gemm_kernel<false, true, 0><<<dim3(8, (Nn + 63) / 64, 16), 256, 0, stream>>>(
                Vc, Smat, nullptr, attc, Nn, 512, 512, 2048, 512, 512,
                512, sbm, sS, 4 * sS, (long)Nn * 512, (long)4 * Nn * 512, 4);
        }

        swt_rec_kernel<<<dim3(Nn, Bn), 128, 0, stream>>>(QA, g0l, g1l, rec);

        // Wo projection
        gemm_kernel<false, true, 0><<<dim3(Dn / 64, (R + 63) / 64, 1), 256, 0, stream>>>(
            rec, Wo + (size_t)l * Dn * Dn, bo + (size_t)l * Dn, tmp,
            R, Dn, Dn, Dn, Dn, Dn, 0, 0, 0, 0, 0, 0, 1);
        ln_kernel<<<R, 128, 0, stream>>>(hbuf, tmp, ln1_g + (size_t)l * Dn, ln1_b + (size_t)l * Dn, x1);

        // FFN (y aliases big0; Smat dead after last AV chunk)
        gemm_kernel<false, true, 1><<<dim3(DFn / 64, (R + 63) / 64, 1), 256, 0, stream>>>(
            x1, W1 + (size_t)l * DFn * Dn, b1 + (size_t)l * DFn, big0,
            R, DFn, Dn, Dn, Dn, DFn, 0, 0, 0, 0, 0, 0, 1);
        gemm_kernel<false, true, 0><<<dim3(Dn / 64, (R + 63) / 64, 1), 256, 0, stream>>>(
            big0, W2 + (size_t)l * Dn * DFn, b2 + (size_t)l * Dn, tmp,
            R, Dn, DFn, DFn, DFn, Dn, 0, 0, 0, 0, 0, 0, 1);
        ln_kernel<<<R, 128, 0, stream>>>(x1, tmp, ln2_g + (size_t)l * Dn, ln2_b + (size_t)l * Dn, hbuf);
    }

    ln_kernel<<<R, 128, 0, stream>>>(hbuf, nullptr, lnf_g, lnf_b, rec);
    gemm_kernel<false, true, 0><<<dim3((Pn + 63) / 64, (R + 63) / 64, 1), 256, 0, stream>>>(
        rec, proj_W, proj_b, ptmp, R, Pn, Dn, Dn, Dn, Pn, 0, 0, 0, 0, 0, 0, 1);
    out_scale_kernel<<<(Bn * Pn * Nn + 255) / 256, 256, 0, stream>>>(ptmp, means, stdev, dec);
}

// Round 4
// 1513.916 us; speedup vs baseline: 3.6751x; 3.6751x over previous
//
#include <hip/hip_runtime.h>
#include <hip/hip_bf16.h>
#include <math.h>

#define Bn 16
#define Sn 512
#define Nn 321
#define Dn 512
#define DFn 2048
#define Pn 96
#define KP 352   // Nn padded to multiple of 32

typedef __bf16 bf16x8 __attribute__((ext_vector_type(8)));
typedef float f32x4 __attribute__((ext_vector_type(4)));
typedef __hip_bfloat16 bf16;

static __device__ __forceinline__ float gelu_exact(float x) {
    return 0.5f * x * (1.0f + erff(x * 0.7071067811865476f));
}

// ---------- fp32 -> bf16 flat convert ----------
__global__ void cvt_kernel(const float* __restrict__ in, bf16* __restrict__ out, int n) {
    int i = (blockIdx.x * 256 + threadIdx.x) * 4;
    if (i + 3 < n) {
        float4 v = *reinterpret_cast<const float4*>(in + i);
        out[i] = __float2bfloat16(v.x);
        out[i + 1] = __float2bfloat16(v.y);
        out[i + 2] = __float2bfloat16(v.z);
        out[i + 3] = __float2bfloat16(v.w);
    } else {
        for (int j = i; j < n; ++j) out[j] = __float2bfloat16(in[j]);
    }
}

// ---------- per-(b,n) mean/std over S ----------
__global__ void stats_kernel(const float* __restrict__ x, float* __restrict__ means,
                             float* __restrict__ stdev) {
    int b = blockIdx.y;
    int n = blockIdx.x * 256 + threadIdx.x;
    if (n >= Nn) return;
    const float* p = x + (size_t)b * Sn * Nn + n;
    float s = 0.f, s2 = 0.f;
    for (int ss = 0; ss < Sn; ++ss) { float v = p[(size_t)ss * Nn]; s += v; s2 += v * v; }
    float mu = s * (1.0f / Sn);
    float var = s2 * (1.0f / Sn) - mu * mu;
    means[b * Nn + n] = mu;
    stdev[b * Nn + n] = sqrtf(var + 1e-5f);
}

// ---------- xT[b,n,s] = (x[b,s,n]-mu)/sd  (bf16 out) ----------
__global__ void transpose_norm_kernel(const float* __restrict__ x,
                                      const float* __restrict__ means,
                                      const float* __restrict__ stdev,
                                      bf16* __restrict__ xT) {
    __shared__ float tile[32][33];
    int b = blockIdx.z;
    int s0 = blockIdx.x * 32, n0 = blockIdx.y * 32;
    int tx = threadIdx.x, ty = threadIdx.y; // 32 x 8
#pragma unroll
    for (int u = 0; u < 4; ++u) {
        int srow = ty + u * 8;
        int n = n0 + tx;
        tile[srow][tx] = (n < Nn) ? x[((size_t)b * Sn + (s0 + srow)) * Nn + n] : 0.f;
    }
    __syncthreads();
#pragma unroll
    for (int u = 0; u < 4; ++u) {
        int n = n0 + ty + u * 8;
        int s = s0 + tx;
        if (n < Nn) {
            float mu = means[b * Nn + n], sd = stdev[b * Nn + n];
            xT[((size_t)b * Nn + n) * Sn + s] = __float2bfloat16((tile[tx][ty + u * 8] - mu) / sd);
        }
    }
}

// ---------- bf16 MFMA GEMM: C[i,j] = sum_k A[i,k]*B[j,k] (+bias) (+gelu) ----------
// A,B bf16 row-major K-contiguous. OUT: 0 fp32 C, 1 bf16 C. EPI: 1 = gelu.
// batch z: zi=z%innerB, zo=z/innerB; element strides per batch dim.
template <int OUT, int EPI>
__global__ __launch_bounds__(256) void mm_kernel(
    const bf16* __restrict__ A, const bf16* __restrict__ Bm,
    const float* __restrict__ bias, void* __restrict__ C,
    int Mdim, int Ndim, int Kdim, int lda, int ldb, int ldc,
    long sAi, long sAo, long sBi, long sBo, long sCi, long sCo, int innerB) {
    int z = blockIdx.z;
    int zi = z % innerB, zo = z / innerB;
    const bf16* Ab = A + (size_t)zi * sAi + (size_t)zo * sAo;
    const bf16* Bb = Bm + (size_t)zi * sBi + (size_t)zo * sBo;
    __shared__ __align__(16) bf16 As[128 * 40];
    __shared__ __align__(16) bf16 Bs[128 * 40];
    int t = threadIdx.x;
    int wave = t >> 6, lane = t & 63;
    int wr = wave >> 1, wc = wave & 1;
    int q = lane >> 4, l16 = lane & 15;
    int i0 = blockIdx.y * 128, j0 = blockIdx.x * 128;
    f32x4 acc[4][4] = {};
    for (int k0 = 0; k0 < Kdim; k0 += 32) {
#pragma unroll
        for (int u = 0; u < 2; ++u) {
            int flat = t + u * 256;          // 0..511
            int row = flat >> 2, kc = (flat & 3) * 8;
            int gi = i0 + row;
            uint4 va = make_uint4(0, 0, 0, 0);
            if (gi < Mdim) va = *reinterpret_cast<const uint4*>(Ab + (size_t)gi * lda + k0 + kc);
            *reinterpret_cast<uint4*>(&As[row * 40 + kc]) = va;
            int gj = j0 + row;
            uint4 vb = make_uint4(0, 0, 0, 0);
            if (gj < Ndim) vb = *reinterpret_cast<const uint4*>(Bb + (size_t)gj * ldb + k0 + kc);
            *reinterpret_cast<uint4*>(&Bs[row * 40 + kc]) = vb;
        }
        __syncthreads();
        // One K=32 MFMA group per stage: lane holds k = (lane>>4)*8 + j, j=0..7.
        bf16x8 af[4], bfr[4];
#pragma unroll
        for (int mi = 0; mi < 4; ++mi)
            af[mi] = *reinterpret_cast<const bf16x8*>(&As[(wr * 64 + mi * 16 + l16) * 40 + q * 8]);
#pragma unroll
        for (int ni = 0; ni < 4; ++ni)
            bfr[ni] = *reinterpret_cast<const bf16x8*>(&Bs[(wc * 64 + ni * 16 + l16) * 40 + q * 8]);
#pragma unroll
        for (int mi = 0; mi < 4; ++mi)
#pragma unroll
            for (int ni = 0; ni < 4; ++ni)
                acc[mi][ni] = __builtin_amdgcn_mfma_f32_16x16x32_bf16(af[mi], bfr[ni], acc[mi][ni], 0, 0, 0);
        __syncthreads();
    }
    size_t cbase = (size_t)zi * sCi + (size_t)zo * sCo;
#pragma unroll
    for (int mi = 0; mi < 4; ++mi) {
#pragma unroll
        for (int r = 0; r < 4; ++r) {
            int gi = i0 + wr * 64 + mi * 16 + q * 4 + r;
            if (gi >= Mdim) continue;
#pragma unroll
            for (int ni = 0; ni < 4; ++ni) {
                int gj = j0 + wc * 64 + ni * 16 + l16;
                if (gj >= Ndim) continue;
                float v = acc[mi][ni][r];
                if (bias) v += bias[gj];
                if (EPI == 1) v = gelu_exact(v);
                size_t cidx = cbase + (size_t)gi * ldc + gj;
                if (OUT == 0) ((float*)C)[cidx] = v;
                else ((bf16*)C)[cidx] = __float2bfloat16(v);
            }
        }
    }
}

// ---------- SWT decomposition: h(b,n,:) fp32 -> coeffs(b,n,4,:) bf16 ----------
__global__ __launch_bounds__(128) void swt_dec_kernel(
    const float* __restrict__ h, const float* __restrict__ h0f,
    const float* __restrict__ h1f, bf16* __restrict__ coeffs) {
    __shared__ float a[2][512];
    int b = blockIdx.y, n = blockIdx.x, t = threadIdx.x;
    const float* hrow = h + ((size_t)b * Nn + n) * Dn;
#pragma unroll
    for (int u = 0; u < 4; ++u) a[0][t + u * 128] = hrow[t + u * 128];
    float f0[3], f1[3];
#pragma unroll
    for (int k = 0; k < 3; ++k) { f0[k] = h0f[n * 3 + k]; f1[k] = h1f[n * 3 + k]; }
    __syncthreads();
    bf16* cb = coeffs + ((size_t)b * Nn + n) * 4 * Dn;
    int cur = 0;
    for (int lev = 0; lev < 3; ++lev) {
        int dil = 1 << lev;
        int pl = 2 * dil - (3 * dil) / 2; // 1,1,2
#pragma unroll
        for (int u = 0; u < 4; ++u) {
            int d = t + u * 128;
            float dv = 0.f, av = 0.f;
#pragma unroll
            for (int k = 0; k < 3; ++k) {
                int idx = (d + k * dil - pl) & 511;
                float xv = a[cur][idx];
                dv += f1[k] * xv;
                av += f0[k] * xv;
            }
            cb[(size_t)(3 - lev) * Dn + d] = __float2bfloat16(dv);
            a[cur ^ 1][d] = av;
        }
        __syncthreads();
        cur ^= 1;
    }
#pragma unroll
    for (int u = 0; u < 4; ++u) cb[t + u * 128] = __float2bfloat16(a[cur][t + u * 128]);
}

// ---------- SWT reconstruction: attn(b,m,n,:) bf16 -> rec(b,n,:) bf16 ----------
__global__ __launch_bounds__(128) void swt_rec_kernel(
    const bf16* __restrict__ attn, const float* __restrict__ g0f,
    const float* __restrict__ g1f, bf16* __restrict__ rec) {
    __shared__ float a[2][512];
    __shared__ float det[512];
    int b = blockIdx.y, n = blockIdx.x, t = threadIdx.x;
    const bf16* base = attn + ((size_t)(b * 4) * Nn + n) * Dn; // m stride = Nn*Dn
#pragma unroll
    for (int u = 0; u < 4; ++u) a[0][t + u * 128] = __bfloat162float(base[t + u * 128]);
    float w0[3], w1[3];
#pragma unroll
    for (int k = 0; k < 3; ++k) { w0[k] = g0f[n * 3 + k]; w1[k] = g1f[n * 3 + k]; }
    int cur = 0;
    for (int i = 0; i < 3; ++i) {
        int dil = 4 >> i;
        int pl = (3 * dil) / 2; // 6,3,1
        const bf16* drow = base + (size_t)(1 + i) * Nn * Dn;
#pragma unroll
        for (int u = 0; u < 4; ++u) det[t + u * 128] = __bfloat162float(drow[t + u * 128]);
        __syncthreads();
#pragma unroll
        for (int u = 0; u < 4; ++u) {
            int d = t + u * 128;
            float s = 0.f;
#pragma unroll
            for (int k = 0; k < 3; ++k) {
                int idx = (d + k * dil - pl) & 511;
                s += w0[k] * a[cur][idx] + w1[k] * det[idx];
            }
            a[cur ^ 1][d] = s * 0.5f;
        }
        __syncthreads();
        cur ^= 1;
    }
    bf16* out = rec + ((size_t)b * Nn + n) * Dn;
#pragma unroll
    for (int u = 0; u < 4; ++u) out[t + u * 128] = __float2bfloat16(a[cur][t + u * 128]);
}

// ---------- transpose-convert: (b,n,m,e) bf16 -> (b,m,e,n-pad352) bf16 ----------
__global__ void tconv_kernel(const bf16* __restrict__ in, bf16* __restrict__ out) {
    __shared__ bf16 tile[32][33];
    int bm = blockIdx.z;
    int b = bm >> 2, m = bm & 3;
    int e0 = blockIdx.x * 32, n0 = blockIdx.y * 32;
    int tx = threadIdx.x, ty = threadIdx.y; // 32 x 8
    const bf16* ib = in + (size_t)b * 4 * Nn * 512 + (size_t)m * 512;
    bf16* ob = out + (size_t)bm * 512 * KP;
#pragma unroll
    for (int u = 0; u < 4; ++u) {
        int n = n0 + ty + u * 8;
        bf16 v = __float2bfloat16(0.f);
        if (n < Nn) v = ib[(size_t)n * 2048 + e0 + tx];
        tile[ty + u * 8][tx] = v;
    }
    __syncthreads();
#pragma unroll
    for (int u = 0; u < 4; ++u) {
        int e = e0 + ty + u * 8;
        int n = n0 + tx;
        if (n < KP) ob[(size_t)e * KP + n] = tile[tx][ty + u * 8];
    }
}

// ---------- column sum of squares from bf16 (b,n,m,e): qn2[bm,e] ----------
__global__ __launch_bounds__(256) void colsq_kernel(const bf16* __restrict__ Q0,
                                                    float* __restrict__ outv) {
    int bm = blockIdx.y;
    int b = bm >> 2, m = bm & 3;
    int e0 = blockIdx.x * 64;
    int tx = threadIdx.x & 63, ty = threadIdx.x >> 6;
    const bf16* base = Q0 + ((size_t)b * Nn * 4 + m) * 512;
    float s = 0.f;
    for (int n = ty; n < Nn; n += 4) {
        float v = __bfloat162float(base[(size_t)n * 2048 + e0 + tx]);
        s += v * v;
    }
    __shared__ float red[4][64];
    red[ty][tx] = s;
    __syncthreads();
    if (ty == 0)
        outv[(size_t)bm * 512 + e0 + tx] = red[0][tx] + red[1][tx] + red[2][tx] + red[3][tx];
}

// ---------- geometric scores + softmax: Smat fp32 in, Pb bf16 out ----------
__global__ __launch_bounds__(256) void wedge_softmax_kernel(
    const float* __restrict__ Smat, const float* __restrict__ qn2,
    const float* __restrict__ kn2, bf16* __restrict__ Pb) {
    int bm = blockIdx.y, l = blockIdx.x, t = threadIdx.x;
    const float* row = Smat + ((size_t)bm * 512 + l) * 512;
    bf16* prow = Pb + ((size_t)bm * 512 + l) * 512;
    const float* kn = kn2 + (size_t)bm * 512;
    float q2 = qn2[(size_t)bm * 512 + l];
    const float scale = rsqrtf(321.0f);
    float v[2];
    float mx = -1e30f;
#pragma unroll
    for (int u = 0; u < 2; ++u) {
        int s = t + u * 256;
        float d = row[s];
        float w = sqrtf(fmaxf(q2 * kn[s] - d * d, 0.f) + 1e-8f);
        float sc = (0.7f * d + 0.3f * w) * scale;
        v[u] = sc;
        mx = fmaxf(mx, sc);
    }
    __shared__ float red[256];
    red[t] = mx;
    __syncthreads();
    for (int o = 128; o > 0; o >>= 1) {
        if (t < o) red[t] = fmaxf(red[t], red[t + o]);
        __syncthreads();
    }
    mx = red[0];
    __syncthreads();
    float sum = 0.f;
#pragma unroll
    for (int u = 0; u < 2; ++u) {
        v[u] = expf(v[u] - mx);
        sum += v[u];
    }
    red[t] = sum;
    __syncthreads();
    for (int o = 128; o > 0; o >>= 1) {
        if (t < o) red[t] += red[t + o];
        __syncthreads();
    }
    float inv = 1.0f / red[0];
#pragma unroll
    for (int u = 0; u < 2; ++u) prow[t + u * 256] = __float2bfloat16(v[u] * inv);
}

// ---------- LayerNorm over D of (A [+ R]); fp32 and/or bf16 out ----------
__global__ __launch_bounds__(128) void ln_kernel(
    const float* __restrict__ A, const float* __restrict__ R,
    const float* __restrict__ g, const float* __restrict__ bb,
    float* __restrict__ outf, bf16* __restrict__ outb) {
    size_t r = blockIdx.x;
    int t = threadIdx.x;
    const float* ra = A + r * Dn;
    float x[4];
    float s = 0.f, s2 = 0.f;
#pragma unroll
    for (int u = 0; u < 4; ++u) {
        int d = t + u * 128;
        float v = ra[d];
        if (R) v += R[r * Dn + d];
        x[u] = v;
        s += v;
        s2 += v * v;
    }
    __shared__ float rs[128], rs2[128];
    rs[t] = s;
    rs2[t] = s2;
    __syncthreads();
    for (int o = 64; o > 0; o >>= 1) {
        if (t < o) { rs[t] += rs[t + o]; rs2[t] += rs2[t + o]; }
        __syncthreads();
    }
    float mean = rs[0] * (1.0f / Dn);
    float var = rs2[0] * (1.0f / Dn) - mean * mean;
    float inv = rsqrtf(var + 1e-5f);
#pragma unroll
    for (int u = 0; u < 4; ++u) {
        int d = t + u * 128;
        float v = (x[u] - mean) * inv * g[d] + bb[d];
        if (outf) outf[r * Dn + d] = v;
        if (outb) outb[r * Dn + d] = __float2bfloat16(v);
    }
}

// ---------- dec[b,p,n] = ptmp[(b,n),p]*sd[b,n] + mu[b,n] ----------
__global__ void out_scale_kernel(const float* __restrict__ ptmp,
                                 const float* __restrict__ means,
                                 const float* __restrict__ stdev, float* __restrict__ dec) {
    int idx = blockIdx.x * 256 + threadIdx.x;
    if (idx >= Bn * Pn * Nn) return;
    int n = idx % Nn;
    int bp = idx / Nn;
    int p = bp % Pn;
    int b = bp / Pn;
    float v = ptmp[((size_t)b * Nn + n) * Pn + p];
    dec[idx] = v * stdev[b * Nn + n] + means[b * Nn + n];
}

extern "C" void kernel_launch(void* const* d_in, const int* in_sizes, int n_in,
                              void* d_out, int out_size, void* d_ws, size_t ws_size,
                              hipStream_t stream) {
    const float* x_enc = (const float*)d_in[0];
    const float* emb_W = (const float*)d_in[1];
    const float* emb_b = (const float*)d_in[2];
    const float* h0 = (const float*)d_in[3];
    const float* h1 = (const float*)d_in[4];
    const float* g0 = (const float*)d_in[5];
    const float* g1 = (const float*)d_in[6];
    const float* Wq = (const float*)d_in[7];
    const float* bq = (const float*)d_in[8];
    const float* Wk = (const float*)d_in[9];
    const float* bk = (const float*)d_in[10];
    const float* Wv = (const float*)d_in[11];
    const float* bv = (const float*)d_in[12];
    const float* Wo = (const float*)d_in[13];
    const float* bo = (const float*)d_in[14];
    const float* W1 = (const float*)d_in[15];
    const float* b1 = (const float*)d_in[16];
    const float* W2 = (const float*)d_in[17];
    const float* b2 = (const float*)d_in[18];
    const float* ln1_g = (const float*)d_in[19];
    const float* ln1_b = (const float*)d_in[20];
    const float* ln2_g = (const float*)d_in[21];
    const float* ln2_b = (const float*)d_in[22];
    const float* lnf_g = (const float*)d_in[23];
    const float* lnf_b = (const float*)d_in[24];
    const float* proj_W = (const float*)d_in[25];
    const float* proj_b = (const float*)d_in[26];

    float* dec = (float*)d_out;
    float* means = dec + (size_t)Bn * Pn * Nn;
    float* stdev = means + (size_t)Bn * Nn;

    // ---- workspace carve (~154 MB) ----
    char* p = (char*)d_ws;
    auto alloc = [&](size_t bytes) { char* r = p; p += (bytes + 255) & ~(size_t)255; return r; };
    const size_t RD = (size_t)Bn * Nn * Dn;        // 2,629,632
    const size_t RQ4 = RD * 4;                     // 10,518,528

    char* WbR = alloc(524288 * 9 + 2097152 * 4 + 98304);  // bf16 weights
    bf16* embWb = (bf16*)WbR;
    bf16* Wqb = embWb + 262144;        // 2 layers x 262144
    bf16* Wkb = Wqb + 2 * 262144;
    bf16* Wvb = Wkb + 2 * 262144;
    bf16* Wob = Wvb + 2 * 262144;
    bf16* W1b = Wob + 2 * 262144;      // 2 x 1,048,576
    bf16* W2b = W1b + 2 * 1048576;
    bf16* projWb = W2b + 2 * 1048576;  // 49,152

    float* hbuf = (float*)alloc(RD * 4);
    char* regC = alloc(RQ4 * 2);       // coeffs_b | attn_b
    char* regQ = alloc(RQ4 * 2);       // Q0b | Smat(16.8M) + ptmp
    char* regK = alloc(RQ4 * 2);       // K0b | Pb(8.4M) + recb + x1b
    char* regV = alloc(RQ4 * 2);       // V0b | yb
    char* regT = alloc((size_t)2 * 64 * 512 * KP * 2);  // xT_b | Qt+Kt | x1+tmp+hfb
    float* qn2 = (float*)alloc(64 * 512 * 4);
    float* kn2 = (float*)alloc(64 * 512 * 4);

    bf16* coeffs_b = (bf16*)regC;
    bf16* attn_b = (bf16*)regC;
    bf16* Q0b = (bf16*)regQ;
    float* Smat = (float*)regQ;                       // 16*512*512 fl per chunk
    float* ptmp = (float*)(regQ + 16777216);
    bf16* K0b = (bf16*)regK;
    bf16* Pb = (bf16*)regK;                           // 16*512*512 bf16 per chunk
    bf16* recb = (bf16*)(regK + 8388608);
    bf16* x1b = (bf16*)(regK + 8388608 + 5259264);
    bf16* V0b = (bf16*)regV;
    bf16* yb = (bf16*)regV;
    bf16* xT_b = (bf16*)regT;
    bf16* Qt = (bf16*)regT;                           // 64*512*352
    bf16* Kt = Qt + (size_t)64 * 512 * KP;
    float* x1 = (float*)regT;
    float* tmp = (float*)(regT + RD * 4);
    bf16* hfb = (bf16*)(regT + RD * 8);

    const int R = Bn * Nn;   // 5136
    const int RQr = R * 4;   // 20544
    const long sbm = (long)4 * Nn * 512;      // per-b stride in Q0b/K0b/V0b/attn (elements)
    const long sS = (long)512 * 512;
    const long sTq = (long)512 * KP;          // per-m stride in Qt/Kt
    const long sTb = 4 * sTq;                 // per-b stride in Qt/Kt

    // ---- weight conversion ----
    auto cvt = [&](const float* src, bf16* dst, int n) {
        cvt_kernel<<<(n / 4 + 255) / 256, 256, 0, stream>>>(src, dst, n);
    };
    cvt(emb_W, embWb, 262144);
    for (int l = 0; l < 2; ++l) {
        cvt(Wq + (size_t)l * 262144, Wqb + (size_t)l * 262144, 262144);
        cvt(Wk + (size_t)l * 262144, Wkb + (size_t)l * 262144, 262144);
        cvt(Wv + (size_t)l * 262144, Wvb + (size_t)l * 262144, 262144);
        cvt(Wo + (size_t)l * 262144, Wob + (size_t)l * 262144, 262144);
        cvt(W1 + (size_t)l * 1048576, W1b + (size_t)l * 1048576, 1048576);
        cvt(W2 + (size_t)l * 1048576, W2b + (size_t)l * 1048576, 1048576);
    }
    cvt(proj_W, projWb, 49152);

    stats_kernel<<<dim3((Nn + 255) / 256, Bn), 256, 0, stream>>>(x_enc, means, stdev);
    transpose_norm_kernel<<<dim3(Sn / 32, (Nn + 31) / 32, Bn), dim3(32, 8), 0, stream>>>(
        x_enc, means, stdev, xT_b);

    // h = xT(5136x512) * emb_W^T + emb_b  -> fp32
    mm_kernel<0, 0><<<dim3(4, (R + 127) / 128, 1), 256, 0, stream>>>(
        xT_b, embWb, emb_b, hbuf, R, Dn, Sn, Sn, Sn, Dn, 0, 0, 0, 0, 0, 0, 1);

    for (int l = 0; l < 2; ++l) {
        const float* h0l = h0 + (size_t)l * Nn * 3;
        const float* h1l = h1 + (size_t)l * Nn * 3;
        const float* g0l = g0 + (size_t)l * Nn * 3;
        const float* g1l = g1 + (size_t)l * Nn * 3;

        swt_dec_kernel<<<dim3(Nn, Bn), 128, 0, stream>>>(hbuf, h0l, h1l, coeffs_b);

        // QKV: rows (b,n,m), K=D -> bf16 (b,n,m,e)
        mm_kernel<1, 0><<<dim3(4, (RQr + 127) / 128, 1), 256, 0, stream>>>(
            coeffs_b, Wqb + (size_t)l * 262144, bq + (size_t)l * Dn, Q0b,
            RQr, Dn, Dn, Dn, Dn, Dn, 0, 0, 0, 0, 0, 0, 1);
        mm_kernel<1, 0><<<dim3(4, (RQr + 127) / 128, 1), 256, 0, stream>>>(
            coeffs_b, Wkb + (size_t)l * 262144, bk + (size_t)l * Dn, K0b,
            RQr, Dn, Dn, Dn, Dn, Dn, 0, 0, 0, 0, 0, 0, 1);
        mm_kernel<1, 0><<<dim3(4, (RQr + 127) / 128, 1), 256, 0, stream>>>(
            coeffs_b, Wvb + (size_t)l * 262144, bv + (size_t)l * Dn, V0b,
            RQr, Dn, Dn, Dn, Dn, Dn, 0, 0, 0, 0, 0, 0, 1);

        colsq_kernel<<<dim3(8, 64), 256, 0, stream>>>(Q0b, qn2);
        colsq_kernel<<<dim3(8, 64), 256, 0, stream>>>(K0b, kn2);
        tconv_kernel<<<dim3(16, 11, 64), dim3(32, 8), 0, stream>>>(Q0b, Qt);
        tconv_kernel<<<dim3(16, 11, 64), dim3(32, 8), 0, stream>>>(K0b, Kt);

        // attention in 4 chunks of 4 batches (16 bm each)
        for (int g = 0; g < 4; ++g) {
            const bf16* Qc = Qt + (size_t)4 * g * sTb;
            const bf16* Kc = Kt + (size_t)4 * g * sTb;
            const bf16* Vc = V0b + (size_t)4 * g * sbm;
            bf16* attc = attn_b + (size_t)4 * g * sbm;

            // dot[bm,l,s] = sum_n Qt[l,n]*Kt[s,n]  (K=352 padded) -> fp32 Smat
            mm_kernel<0, 0><<<dim3(4, 4, 16), 256, 0, stream>>>(
                Qc, Kc, nullptr, Smat, 512, 512, KP, KP, KP, 512,
                sTq, sTb, sTq, sTb, sS, 4 * sS, 4);

            wedge_softmax_kernel<<<dim3(512, 16), 256, 0, stream>>>(
                Smat, qn2 + (size_t)16 * g * 512, kn2 + (size_t)16 * g * 512, Pb);

            // attn[b,m,n,l] = sum_s V0b[(b,n,m),s] * Pb[bm,l,s] -> bf16
            mm_kernel<1, 0><<<dim3(4, (Nn + 127) / 128, 16), 256, 0, stream>>>(
                Vc, Pb, nullptr, attc, Nn, 512, 512, 2048, 512, 512,
                512, sbm, sS, 4 * sS, (long)Nn * 512, (long)4 * Nn * 512, 4);
        }

        swt_rec_kernel<<<dim3(Nn, Bn), 128, 0, stream>>>(attn_b, g0l, g1l, recb);

        // Wo -> tmp fp32
        mm_kernel<0, 0><<<dim3(4, (R + 127) / 128, 1), 256, 0, stream>>>(
            recb, Wob + (size_t)l * 262144, bo + (size_t)l * Dn, tmp,
            R, Dn, Dn, Dn, Dn, Dn, 0, 0, 0, 0, 0, 0, 1);
        ln_kernel<<<R, 128, 0, stream>>>(hbuf, tmp, ln1_g + (size_t)l * Dn,
                                         ln1_b + (size_t)l * Dn, x1, x1b);

        // FFN1 (gelu, bf16 out)
        mm_kernel<1, 1><<<dim3(16, (R + 127) / 128, 1), 256, 0, stream>>>(
            x1b, W1b + (size_t)l * 1048576, b1 + (size_t)l * DFn, yb,
            R, DFn, Dn, Dn, Dn, DFn, 0, 0, 0, 0, 0, 0, 1);
        // FFN2 -> tmp fp32
        mm_kernel<0, 0><<<dim3(4, (R + 127) / 128, 1), 256, 0, stream>>>(
            yb, W2b + (size_t)l * 1048576, b2 + (size_t)l * Dn, tmp,
            R, Dn, DFn, DFn, DFn, Dn, 0, 0, 0, 0, 0, 0, 1);
        ln_kernel<<<R, 128, 0, stream>>>(x1, tmp, ln2_g + (size_t)l * Dn,
                                         ln2_b + (size_t)l * Dn, hbuf, nullptr);
    }

    ln_kernel<<<R, 128, 0, stream>>>(hbuf, nullptr, lnf_g, lnf_b, nullptr, hfb);
    mm_kernel<0, 0><<<dim3(1, (R + 127) / 128, 1), 256, 0, stream>>>(
        hfb, projWb, proj_b, ptmp, R, Pn, Dn, Dn, Dn, Pn, 0, 0, 0, 0, 0, 0, 1);
    out_scale_kernel<<<(Bn * Pn * Nn + 255) / 256, 256, 0, stream>>>(ptmp, means, stdev, dec);
}

// Round 6
// 1091.589 us; speedup vs baseline: 5.0970x; 1.3869x over previous
//
#include <hip/hip_runtime.h>
#include <hip/hip_bf16.h>
#include <math.h>
#include <stdint.h>

#define Bn 16
#define Sn 512
#define Nn 321
#define Dn 512
#define DFn 2048
#define Pn 96
#define KP 352   // Nn padded to multiple of 32

typedef __bf16 bf16x8 __attribute__((ext_vector_type(8)));
typedef float f32x4 __attribute__((ext_vector_type(4)));
typedef __hip_bfloat16 bf16;

static __device__ __forceinline__ float gelu_exact(float x) {
    return 0.5f * x * (1.0f + erff(x * 0.7071067811865476f));
}

static __device__ __forceinline__ void gld16(const void* g, void* l) {
    __builtin_amdgcn_global_load_lds(
        (const __attribute__((address_space(1))) void*)(uintptr_t)g,
        (__attribute__((address_space(3))) void*)(uintptr_t)l, 16, 0, 0);
}

// ---------- fused fp32 -> bf16 weight conversion (single launch) ----------
struct CvtPack {
    const float* src[14];
    bf16* dst[14];
    int cnt[14];
};
__global__ void cvt_all_kernel(CvtPack p) {
    int seg = blockIdx.y;
    int n = p.cnt[seg];
    const float* s = p.src[seg];
    bf16* d = p.dst[seg];
    int i = (blockIdx.x * 256 + threadIdx.x) * 4;
    if (i + 3 < n) {
        float4 v = *reinterpret_cast<const float4*>(s + i);
        d[i] = __float2bfloat16(v.x);
        d[i + 1] = __float2bfloat16(v.y);
        d[i + 2] = __float2bfloat16(v.z);
        d[i + 3] = __float2bfloat16(v.w);
    }
}

// ---------- per-(b,n) mean/std over S ----------
__global__ void stats_kernel(const float* __restrict__ x, float* __restrict__ means,
                             float* __restrict__ stdev) {
    int b = blockIdx.y;
    int n = blockIdx.x * 256 + threadIdx.x;
    if (n >= Nn) return;
    const float* p = x + (size_t)b * Sn * Nn + n;
    float s = 0.f, s2 = 0.f;
    for (int ss = 0; ss < Sn; ++ss) { float v = p[(size_t)ss * Nn]; s += v; s2 += v * v; }
    float mu = s * (1.0f / Sn);
    float var = s2 * (1.0f / Sn) - mu * mu;
    means[b * Nn + n] = mu;
    stdev[b * Nn + n] = sqrtf(var + 1e-5f);
}

// ---------- xT[b,n,s] = (x[b,s,n]-mu)/sd  (bf16 out) ----------
__global__ void transpose_norm_kernel(const float* __restrict__ x,
                                      const float* __restrict__ means,
                                      const float* __restrict__ stdev,
                                      bf16* __restrict__ xT) {
    __shared__ float tile[32][33];
    int b = blockIdx.z;
    int s0 = blockIdx.x * 32, n0 = blockIdx.y * 32;
    int tx = threadIdx.x, ty = threadIdx.y; // 32 x 8
#pragma unroll
    for (int u = 0; u < 4; ++u) {
        int srow = ty + u * 8;
        int n = n0 + tx;
        tile[srow][tx] = (n < Nn) ? x[((size_t)b * Sn + (s0 + srow)) * Nn + n] : 0.f;
    }
    __syncthreads();
#pragma unroll
    for (int u = 0; u < 4; ++u) {
        int n = n0 + ty + u * 8;
        int s = s0 + tx;
        if (n < Nn) {
            float mu = means[b * Nn + n], sd = stdev[b * Nn + n];
            xT[((size_t)b * Nn + n) * Sn + s] = __float2bfloat16((tile[tx][ty + u * 8] - mu) / sd);
        }
    }
}

// ---------- bf16 MFMA GEMM (m97 structure): C[i,j] = sum_k A[i,k]*B[j,k] ----------
// global_load_lds(16B) staging into unpadded [128][32] LDS, XOR-swizzled.
template <int OUT, int EPI>
__global__ __launch_bounds__(256) void mm_kernel(
    const bf16* __restrict__ A, const bf16* __restrict__ Bm,
    const float* __restrict__ bias, void* __restrict__ C,
    int Mdim, int Ndim, int Kdim, int lda, int ldb, int ldc,
    long sAi, long sAo, long sBi, long sBo, long sCi, long sCo, int innerB) {
    int z = blockIdx.z;
    int zi = z % innerB, zo = z / innerB;
    const bf16* Ab = A + (size_t)zi * sAi + (size_t)zo * sAo;
    const bf16* Bb = Bm + (size_t)zi * sBi + (size_t)zo * sBo;
    __shared__ __align__(16) bf16 As[128 * 32];
    __shared__ __align__(16) bf16 Bs[128 * 32];
    int t = threadIdx.x;
    int wave = t >> 6, lane = t & 63;
    int wr = wave >> 1, wc = wave & 1;
    int q = lane >> 4, l16 = lane & 15;
    int i0 = blockIdx.y * 128, j0 = blockIdx.x * 128;

    int srow0 = t >> 2;              // + u*64
    int scol = (t & 3) * 8;          // LDS col base (element units)
    f32x4 acc[4][4] = {};

    for (int k0 = 0; k0 < Kdim; k0 += 32) {
#pragma unroll
        for (int u = 0; u < 2; ++u) {
            int row = u * 64 + srow0;
            int gcol = scol ^ (((row >> 1) & 3) << 3);   // global col for this LDS slot
            int gi = i0 + row; if (gi >= Mdim) gi = Mdim - 1;
            gld16(Ab + (size_t)gi * lda + k0 + gcol, &As[u * 2048 + wave * 512]);
            int gj = j0 + row; if (gj >= Ndim) gj = Ndim - 1;
            gld16(Bb + (size_t)gj * ldb + k0 + gcol, &Bs[u * 2048 + wave * 512]);
        }
        __syncthreads();
        bf16x8 af[4], bfr[4];
#pragma unroll
        for (int mi = 0; mi < 4; ++mi) {
            int r = wr * 64 + mi * 16 + l16;
            int cl = (q * 8) ^ (((r >> 1) & 3) << 3);
            af[mi] = *reinterpret_cast<const bf16x8*>(&As[r * 32 + cl]);
        }
#pragma unroll
        for (int ni = 0; ni < 4; ++ni) {
            int r = wc * 64 + ni * 16 + l16;
            int cl = (q * 8) ^ (((r >> 1) & 3) << 3);
            bfr[ni] = *reinterpret_cast<const bf16x8*>(&Bs[r * 32 + cl]);
        }
#pragma unroll
        for (int mi = 0; mi < 4; ++mi)
#pragma unroll
            for (int ni = 0; ni < 4; ++ni)
                acc[mi][ni] = __builtin_amdgcn_mfma_f32_16x16x32_bf16(af[mi], bfr[ni], acc[mi][ni], 0, 0, 0);
        __syncthreads();
    }
    size_t cbase = (size_t)zi * sCi + (size_t)zo * sCo;
#pragma unroll
    for (int mi = 0; mi < 4; ++mi) {
#pragma unroll
        for (int r = 0; r < 4; ++r) {
            int gi = i0 + wr * 64 + mi * 16 + q * 4 + r;
            if (gi >= Mdim) continue;
#pragma unroll
            for (int ni = 0; ni < 4; ++ni) {
                int gj = j0 + wc * 64 + ni * 16 + l16;
                if (gj >= Ndim) continue;
                float v = acc[mi][ni][r];
                if (bias) v += bias[gj];
                if (EPI == 1) v = gelu_exact(v);
                size_t cidx = cbase + (size_t)gi * ldc + gj;
                if (OUT == 0) ((float*)C)[cidx] = v;
                else ((bf16*)C)[cidx] = __float2bfloat16(v);
            }
        }
    }
}

// ---------- SWT decomposition: h(b,n,:) fp32 -> coeffs(b,n,4,:) bf16 ----------
__global__ __launch_bounds__(128) void swt_dec_kernel(
    const float* __restrict__ h, const float* __restrict__ h0f,
    const float* __restrict__ h1f, bf16* __restrict__ coeffs) {
    __shared__ float a[2][512];
    int b = blockIdx.y, n = blockIdx.x, t = threadIdx.x;
    const float* hrow = h + ((size_t)b * Nn + n) * Dn;
#pragma unroll
    for (int u = 0; u < 4; ++u) a[0][t + u * 128] = hrow[t + u * 128];
    float f0[3], f1[3];
#pragma unroll
    for (int k = 0; k < 3; ++k) { f0[k] = h0f[n * 3 + k]; f1[k] = h1f[n * 3 + k]; }
    __syncthreads();
    bf16* cb = coeffs + ((size_t)b * Nn + n) * 4 * Dn;
    int cur = 0;
    for (int lev = 0; lev < 3; ++lev) {
        int dil = 1 << lev;
        int pl = 2 * dil - (3 * dil) / 2; // 1,1,2
#pragma unroll
        for (int u = 0; u < 4; ++u) {
            int d = t + u * 128;
            float dv = 0.f, av = 0.f;
#pragma unroll
            for (int k = 0; k < 3; ++k) {
                int idx = (d + k * dil - pl) & 511;
                float xv = a[cur][idx];
                dv += f1[k] * xv;
                av += f0[k] * xv;
            }
            cb[(size_t)(3 - lev) * Dn + d] = __float2bfloat16(dv);
            a[cur ^ 1][d] = av;
        }
        __syncthreads();
        cur ^= 1;
    }
#pragma unroll
    for (int u = 0; u < 4; ++u) cb[t + u * 128] = __float2bfloat16(a[cur][t + u * 128]);
}

// ---------- SWT reconstruction: attn(b,m,n,:) bf16 -> rec(b,n,:) bf16 ----------
__global__ __launch_bounds__(128) void swt_rec_kernel(
    const bf16* __restrict__ attn, const float* __restrict__ g0f,
    const float* __restrict__ g1f, bf16* __restrict__ rec) {
    __shared__ float a[2][512];
    __shared__ float det[512];
    int b = blockIdx.y, n = blockIdx.x, t = threadIdx.x;
    const bf16* base = attn + ((size_t)(b * 4) * Nn + n) * Dn;
#pragma unroll
    for (int u = 0; u < 4; ++u) a[0][t + u * 128] = __bfloat162float(base[t + u * 128]);
    float w0[3], w1[3];
#pragma unroll
    for (int k = 0; k < 3; ++k) { w0[k] = g0f[n * 3 + k]; w1[k] = g1f[n * 3 + k]; }
    int cur = 0;
    for (int i = 0; i < 3; ++i) {
        int dil = 4 >> i;
        int pl = (3 * dil) / 2; // 6,3,1
        const bf16* drow = base + (size_t)(1 + i) * Nn * Dn;
#pragma unroll
        for (int u = 0; u < 4; ++u) det[t + u * 128] = __bfloat162float(drow[t + u * 128]);
        __syncthreads();
#pragma unroll
        for (int u = 0; u < 4; ++u) {
            int d = t + u * 128;
            float s = 0.f;
#pragma unroll
            for (int k = 0; k < 3; ++k) {
                int idx = (d + k * dil - pl) & 511;
                s += w0[k] * a[cur][idx] + w1[k] * det[idx];
            }
            a[cur ^ 1][d] = s * 0.5f;
        }
        __syncthreads();
        cur ^= 1;
    }
    bf16* out = rec + ((size_t)b * Nn + n) * Dn;
#pragma unroll
    for (int u = 0; u < 4; ++u) out[t + u * 128] = __float2bfloat16(a[cur][t + u * 128]);
}

// ---------- transpose-convert: (b,n,m,e) bf16 -> (b,m,e,n-pad352) bf16 ----------
__global__ void tconv_kernel(const bf16* __restrict__ in, bf16* __restrict__ out) {
    __shared__ bf16 tile[32][33];
    int bm = blockIdx.z;
    int b = bm >> 2, m = bm & 3;
    int e0 = blockIdx.x * 32, n0 = blockIdx.y * 32;
    int tx = threadIdx.x, ty = threadIdx.y; // 32 x 8
    const bf16* ib = in + (size_t)b * 4 * Nn * 512 + (size_t)m * 512;
    bf16* ob = out + (size_t)bm * 512 * KP;
#pragma unroll
    for (int u = 0; u < 4; ++u) {
        int n = n0 + ty + u * 8;
        bf16 v = __float2bfloat16(0.f);
        if (n < Nn) v = ib[(size_t)n * 2048 + e0 + tx];
        tile[ty + u * 8][tx] = v;
    }
    __syncthreads();
#pragma unroll
    for (int u = 0; u < 4; ++u) {
        int e = e0 + ty + u * 8;
        int n = n0 + tx;
        if (n < KP) ob[(size_t)e * KP + n] = tile[tx][ty + u * 8];
    }
}

// ---------- column sum of squares from bf16 (b,n,m,e): qn2[bm,e] ----------
__global__ __launch_bounds__(256) void colsq_kernel(const bf16* __restrict__ Q0,
                                                    float* __restrict__ outv) {
    int bm = blockIdx.y;
    int b = bm >> 2, m = bm & 3;
    int e0 = blockIdx.x * 64;
    int tx = threadIdx.x & 63, ty = threadIdx.x >> 6;
    const bf16* base = Q0 + ((size_t)b * Nn * 4 + m) * 512;
    float s = 0.f;
    for (int n = ty; n < Nn; n += 4) {
        float v = __bfloat162float(base[(size_t)n * 2048 + e0 + tx]);
        s += v * v;
    }
    __shared__ float red[4][64];
    red[ty][tx] = s;
    __syncthreads();
    if (ty == 0)
        outv[(size_t)bm * 512 + e0 + tx] = red[0][tx] + red[1][tx] + red[2][tx] + red[3][tx];
}

// ---------- geometric scores + softmax, IN PLACE on bf16 Smat[bm,l,s] ----------
__global__ __launch_bounds__(256) void wedge_softmax_kernel(
    bf16* __restrict__ Smat, const float* __restrict__ qn2, const float* __restrict__ kn2) {
    int bm = blockIdx.y, l = blockIdx.x, t = threadIdx.x;
    bf16* row = Smat + ((size_t)bm * 512 + l) * 512;
    const float* kn = kn2 + (size_t)bm * 512;
    float q2 = qn2[(size_t)bm * 512 + l];
    const float scale = rsqrtf(321.0f);
    float v[2];
    float mx = -1e30f;
#pragma unroll
    for (int u = 0; u < 2; ++u) {
        int s = t + u * 256;
        float d = __bfloat162float(row[s]);
        float w = sqrtf(fmaxf(q2 * kn[s] - d * d, 0.f) + 1e-8f);
        float sc = (0.7f * d + 0.3f * w) * scale;
        v[u] = sc;
        mx = fmaxf(mx, sc);
    }
    __shared__ float red[256];
    red[t] = mx;
    __syncthreads();
    for (int o = 128; o > 0; o >>= 1) {
        if (t < o) red[t] = fmaxf(red[t], red[t + o]);
        __syncthreads();
    }
    mx = red[0];
    __syncthreads();
    float sum = 0.f;
#pragma unroll
    for (int u = 0; u < 2; ++u) {
        v[u] = expf(v[u] - mx);
        sum += v[u];
    }
    red[t] = sum;
    __syncthreads();
    for (int o = 128; o > 0; o >>= 1) {
        if (t < o) red[t] += red[t + o];
        __syncthreads();
    }
    float inv = 1.0f / red[0];
#pragma unroll
    for (int u = 0; u < 2; ++u) row[t + u * 256] = __float2bfloat16(v[u] * inv);
}

// ---------- LayerNorm over D of (A [+ R]); fp32 and/or bf16 out ----------
__global__ __launch_bounds__(128) void ln_kernel(
    const float* __restrict__ A, const float* __restrict__ R,
    const float* __restrict__ g, const float* __restrict__ bb,
    float* __restrict__ outf, bf16* __restrict__ outb) {
    size_t r = blockIdx.x;
    int t = threadIdx.x;
    const float* ra = A + r * Dn;
    float x[4];
    float s = 0.f, s2 = 0.f;
#pragma unroll
    for (int u = 0; u < 4; ++u) {
        int d = t + u * 128;
        float v = ra[d];
        if (R) v += R[r * Dn + d];
        x[u] = v;
        s += v;
        s2 += v * v;
    }
    __shared__ float rs[128], rs2[128];
    rs[t] = s;
    rs2[t] = s2;
    __syncthreads();
    for (int o = 64; o > 0; o >>= 1) {
        if (t < o) { rs[t] += rs[t + o]; rs2[t] += rs2[t + o]; }
        __syncthreads();
    }
    float mean = rs[0] * (1.0f / Dn);
    float var = rs2[0] * (1.0f / Dn) - mean * mean;
    float inv = rsqrtf(var + 1e-5f);
#pragma unroll
    for (int u = 0; u < 4; ++u) {
        int d = t + u * 128;
        float v = (x[u] - mean) * inv * g[d] + bb[d];
        if (outf) outf[r * Dn + d] = v;
        if (outb) outb[r * Dn + d] = __float2bfloat16(v);
    }
}

// ---------- dec[b,p,n] = ptmp[(b,n),p]*sd[b,n] + mu[b,n] ----------
__global__ void out_scale_kernel(const float* __restrict__ ptmp,
                                 const float* __restrict__ means,
                                 const float* __restrict__ stdev, float* __restrict__ dec) {
    int idx = blockIdx.x * 256 + threadIdx.x;
    if (idx >= Bn * Pn * Nn) return;
    int n = idx % Nn;
    int bp = idx / Nn;
    int p = bp % Pn;
    int b = bp / Pn;
    float v = ptmp[((size_t)b * Nn + n) * Pn + p];
    dec[idx] = v * stdev[b * Nn + n] + means[b * Nn + n];
}

extern "C" void kernel_launch(void* const* d_in, const int* in_sizes, int n_in,
                              void* d_out, int out_size, void* d_ws, size_t ws_size,
                              hipStream_t stream) {
    const float* x_enc = (const float*)d_in[0];
    const float* emb_W = (const float*)d_in[1];
    const float* emb_b = (const float*)d_in[2];
    const float* h0 = (const float*)d_in[3];
    const float* h1 = (const float*)d_in[4];
    const float* g0 = (const float*)d_in[5];
    const float* g1 = (const float*)d_in[6];
    const float* Wq = (const float*)d_in[7];
    const float* bq = (const float*)d_in[8];
    const float* Wk = (const float*)d_in[9];
    const float* bk = (const float*)d_in[10];
    const float* Wv = (const float*)d_in[11];
    const float* bv = (const float*)d_in[12];
    const float* Wo = (const float*)d_in[13];
    const float* bo = (const float*)d_in[14];
    const float* W1 = (const float*)d_in[15];
    const float* b1 = (const float*)d_in[16];
    const float* W2 = (const float*)d_in[17];
    const float* b2 = (const float*)d_in[18];
    const float* ln1_g = (const float*)d_in[19];
    const float* ln1_b = (const float*)d_in[20];
    const float* ln2_g = (const float*)d_in[21];
    const float* ln2_b = (const float*)d_in[22];
    const float* lnf_g = (const float*)d_in[23];
    const float* lnf_b = (const float*)d_in[24];
    const float* proj_W = (const float*)d_in[25];
    const float* proj_b = (const float*)d_in[26];

    float* dec = (float*)d_out;
    float* means = dec + (size_t)Bn * Pn * Nn;
    float* stdev = means + (size_t)Bn * Nn;

    // ---- workspace carve (~154 MB; Smat aliases regQ+regK span) ----
    char* p = (char*)d_ws;
    auto alloc = [&](size_t bytes) { char* r = p; p += (bytes + 255) & ~(size_t)255; return r; };
    const size_t RD = (size_t)Bn * Nn * Dn;        // 2,629,632 elements
    const size_t RQ4 = RD * 4;                     // 10,518,528

    bf16* embWb = (bf16*)alloc(262144 * 2);
    bf16* Wqb = (bf16*)alloc(2 * 262144 * 2);
    bf16* Wkb = (bf16*)alloc(2 * 262144 * 2);
    bf16* Wvb = (bf16*)alloc(2 * 262144 * 2);
    bf16* Wob = (bf16*)alloc(2 * 262144 * 2);
    bf16* W1b = (bf16*)alloc(2 * 1048576 * 2);
    bf16* W2b = (bf16*)alloc(2 * 1048576 * 2);
    bf16* projWb = (bf16*)alloc(49152 * 2);

    float* hbuf = (float*)alloc(RD * 4);
    char* regC = alloc(RQ4 * 2);                     // coeffs_b | attn_b
    char* regQ = alloc(RQ4 * 2);                     // Q0b | Smat(head) | recb,x1b | ptmp
    char* regK = alloc(RQ4 * 2);                     // K0b | Smat(tail)
    char* regV = alloc(RQ4 * 2);                     // V0b | yb
    char* regT = alloc((size_t)2 * 64 * 512 * KP * 2); // xT_b | Qt+Kt | x1,tmp,hfb
    float* qn2 = (float*)alloc(64 * 512 * 4);
    float* kn2 = (float*)alloc(64 * 512 * 4);

    bf16* coeffs_b = (bf16*)regC;
    bf16* attn_b = (bf16*)regC;
    bf16* Q0b = (bf16*)regQ;
    bf16* Smat = (bf16*)regQ;                        // 64*512*512 bf16 = 33.5MB, spans regQ+regK
    bf16* recb = (bf16*)regQ;                        // after Smat dead (swt_rec follows AV)
    bf16* x1b = (bf16*)(regQ + RD * 2);              // after recb's producer; dead before next QKV
    float* ptmp = (float*)regQ;                      // final projection scratch
    bf16* K0b = (bf16*)regK;
    bf16* V0b = (bf16*)regV;
    bf16* yb = (bf16*)regV;
    bf16* Qt = (bf16*)regT;                          // 64*512*352
    bf16* Kt = Qt + (size_t)64 * 512 * KP;
    bf16* xT_b = (bf16*)regT;                        // dead before Qt written
    float* x1 = (float*)regT;
    float* tmp = (float*)(regT + RD * 4);
    bf16* hfb = (bf16*)(regT + RD * 8);

    const int R = Bn * Nn;   // 5136
    const int RQr = R * 4;   // 20544
    const long sbm = (long)4 * Nn * 512;      // per-b stride in Q0b/K0b/V0b/attn
    const long sS = (long)512 * 512;
    const long sTq = (long)512 * KP;          // per-m stride in Qt/Kt
    const long sTb = 4 * sTq;                 // per-b stride in Qt/Kt

    // ---- fused weight conversion (1 launch) ----
    CvtPack cp;
    int ci = 0;
    auto addcvt = [&](const float* s, bf16* d, int n) { cp.src[ci] = s; cp.dst[ci] = d; cp.cnt[ci] = n; ++ci; };
    addcvt(emb_W, embWb, 262144);
    for (int l = 0; l < 2; ++l) {
        addcvt(Wq + (size_t)l * 262144, Wqb + (size_t)l * 262144, 262144);
        addcvt(Wk + (size_t)l * 262144, Wkb + (size_t)l * 262144, 262144);
        addcvt(Wv + (size_t)l * 262144, Wvb + (size_t)l * 262144, 262144);
        addcvt(Wo + (size_t)l * 262144, Wob + (size_t)l * 262144, 262144);
        addcvt(W1 + (size_t)l * 1048576, W1b + (size_t)l * 1048576, 1048576);
        addcvt(W2 + (size_t)l * 1048576, W2b + (size_t)l * 1048576, 1048576);
    }
    addcvt(proj_W, projWb, 49152);
    cvt_all_kernel<<<dim3(1048576 / 4 / 256, 14), 256, 0, stream>>>(cp);

    stats_kernel<<<dim3((Nn + 255) / 256, Bn), 256, 0, stream>>>(x_enc, means, stdev);
    transpose_norm_kernel<<<dim3(Sn / 32, (Nn + 31) / 32, Bn), dim3(32, 8), 0, stream>>>(
        x_enc, means, stdev, xT_b);

    // h = xT(5136x512) * emb_W^T + emb_b  -> fp32
    mm_kernel<0, 0><<<dim3(4, (R + 127) / 128, 1), 256, 0, stream>>>(
        xT_b, embWb, emb_b, hbuf, R, Dn, Sn, Sn, Sn, Dn, 0, 0, 0, 0, 0, 0, 1);

    for (int l = 0; l < 2; ++l) {
        const float* h0l = h0 + (size_t)l * Nn * 3;
        const float* h1l = h1 + (size_t)l * Nn * 3;
        const float* g0l = g0 + (size_t)l * Nn * 3;
        const float* g1l = g1 + (size_t)l * Nn * 3;

        swt_dec_kernel<<<dim3(Nn, Bn), 128, 0, stream>>>(hbuf, h0l, h1l, coeffs_b);

        // QKV: rows (b,n,m), K=D -> bf16 (b,n,m,e)
        mm_kernel<1, 0><<<dim3(4, (RQr + 127) / 128, 1), 256, 0, stream>>>(
            coeffs_b, Wqb + (size_t)l * 262144, bq + (size_t)l * Dn, Q0b,
            RQr, Dn, Dn, Dn, Dn, Dn, 0, 0, 0, 0, 0, 0, 1);
        mm_kernel<1, 0><<<dim3(4, (RQr + 127) / 128, 1), 256, 0, stream>>>(
            coeffs_b, Wkb + (size_t)l * 262144, bk + (size_t)l * Dn, K0b,
            RQr, Dn, Dn, Dn, Dn, Dn, 0, 0, 0, 0, 0, 0, 1);
        mm_kernel<1, 0><<<dim3(4, (RQr + 127) / 128, 1), 256, 0, stream>>>(
            coeffs_b, Wvb + (size_t)l * 262144, bv + (size_t)l * Dn, V0b,
            RQr, Dn, Dn, Dn, Dn, Dn, 0, 0, 0, 0, 0, 0, 1);

        colsq_kernel<<<dim3(8, 64), 256, 0, stream>>>(Q0b, qn2);
        colsq_kernel<<<dim3(8, 64), 256, 0, stream>>>(K0b, kn2);
        tconv_kernel<<<dim3(16, 11, 64), dim3(32, 8), 0, stream>>>(Q0b, Qt);
        tconv_kernel<<<dim3(16, 11, 64), dim3(32, 8), 0, stream>>>(K0b, Kt);

        // dot[bm,l,s] = sum_n Qt[l,n]*Kt[s,n]  -> bf16 Smat (Q0b/K0b dead now)
        mm_kernel<1, 0><<<dim3(4, 4, 64), 256, 0, stream>>>(
            Qt, Kt, nullptr, Smat, 512, 512, KP, KP, KP, 512,
            sTq, sTb, sTq, sTb, sS, 4 * sS, 4);

        wedge_softmax_kernel<<<dim3(512, 64), 256, 0, stream>>>(Smat, qn2, kn2);

        // attn[b,m,n,l] = sum_s V0b[(b,n,m),s] * Smat[bm,l,s] -> bf16
        mm_kernel<1, 0><<<dim3(4, (Nn + 127) / 128, 64), 256, 0, stream>>>(
            V0b, Smat, nullptr, attn_b, Nn, 512, 512, 2048, 512, 512,
            512, sbm, sS, 4 * sS, (long)Nn * 512, (long)4 * Nn * 512, 4);

        // Smat dead; recb overwrites its head
        swt_rec_kernel<<<dim3(Nn, Bn), 128, 0, stream>>>(attn_b, g0l, g1l, recb);

        // Wo -> tmp fp32
        mm_kernel<0, 0><<<dim3(4, (R + 127) / 128, 1), 256, 0, stream>>>(
            recb, Wob + (size_t)l * 262144, bo + (size_t)l * Dn, tmp,
            R, Dn, Dn, Dn, Dn, Dn, 0, 0, 0, 0, 0, 0, 1);
        ln_kernel<<<R, 128, 0, stream>>>(hbuf, tmp, ln1_g + (size_t)l * Dn,
                                         ln1_b + (size_t)l * Dn, x1, x1b);

        // FFN1 (gelu, bf16 out)
        mm_kernel<1, 1><<<dim3(16, (R + 127) / 128, 1), 256, 0, stream>>>(
            x1b, W1b + (size_t)l * 1048576, b1 + (size_t)l * DFn, yb,
            R, DFn, Dn, Dn, Dn, DFn, 0, 0, 0, 0, 0, 0, 1);
        // FFN2 -> tmp fp32
        mm_kernel<0, 0><<<dim3(4, (R + 127) / 128, 1), 256, 0, stream>>>(
            yb, W2b + (size_t)l * 1048576, b2 + (size_t)l * Dn, tmp,
            R, Dn, DFn, DFn, DFn, Dn, 0, 0, 0, 0, 0, 0, 1);
        ln_kernel<<<R, 128, 0, stream>>>(x1, tmp, ln2_g + (size_t)l * Dn,
                                         ln2_b + (size_t)l * Dn, hbuf, nullptr);
    }

    ln_kernel<<<R, 128, 0, stream>>>(hbuf, nullptr, lnf_g, lnf_b, nullptr, hfb);
    mm_kernel<0, 0><<<dim3(1, (R + 127) / 128, 1), 256, 0, stream>>>(
        hfb, projWb, proj_b, ptmp, R, Pn, Dn, Dn, Dn, Pn, 0, 0, 0, 0, 0, 0, 1);
    out_scale_kernel<<<(Bn * Pn * Nn + 255) / 256, 256, 0, stream>>>(ptmp, means, stdev, dec);
}

// Round 7
// 1002.749 us; speedup vs baseline: 5.5486x; 1.0886x over previous
//
#include <hip/hip_runtime.h>
#include <hip/hip_bf16.h>
#include <math.h>
#include <stdint.h>

#define Bn 16
#define Sn 512
#define Nn 321
#define Dn 512
#define DFn 2048
#define Pn 96
#define KP 352   // Nn padded to multiple of 32

typedef __bf16 bf16x8 __attribute__((ext_vector_type(8)));
typedef float f32x4 __attribute__((ext_vector_type(4)));
typedef __hip_bfloat16 bf16;

static __device__ __forceinline__ float gelu_exact(float x) {
    return 0.5f * x * (1.0f + erff(x * 0.7071067811865476f));
}

static __device__ __forceinline__ void gld16(const void* g, void* l) {
    __builtin_amdgcn_global_load_lds(
        (const __attribute__((address_space(1))) void*)(uintptr_t)g,
        (__attribute__((address_space(3))) void*)(uintptr_t)l, 16, 0, 0);
}

// ---------- fused fp32 -> bf16 weight conversion (single launch) ----------
struct CvtPack {
    const float* src[14];
    bf16* dst[14];
    int cnt[14];
};
__global__ void cvt_all_kernel(CvtPack p) {
    int seg = blockIdx.y;
    int n = p.cnt[seg];
    const float* s = p.src[seg];
    bf16* d = p.dst[seg];
    int i = (blockIdx.x * 256 + threadIdx.x) * 4;
    if (i + 3 < n) {
        float4 v = *reinterpret_cast<const float4*>(s + i);
        d[i] = __float2bfloat16(v.x);
        d[i + 1] = __float2bfloat16(v.y);
        d[i + 2] = __float2bfloat16(v.z);
        d[i + 3] = __float2bfloat16(v.w);
    }
}

// ---------- combined QK bias: bqk[l][0:512]=bq[l], [512:1024]=bk[l] ----------
__global__ void bias_pack_kernel(const float* __restrict__ bq, const float* __restrict__ bk,
                                 float* __restrict__ bqk) {
    int idx = blockIdx.x * 256 + threadIdx.x;
    if (idx >= 2048) return;
    int l = idx >> 10, j = idx & 1023;
    bqk[idx] = (j < 512) ? bq[l * 512 + j] : bk[l * 512 + j - 512];
}

// ---------- per-(b,n) mean/std over S ----------
__global__ void stats_kernel(const float* __restrict__ x, float* __restrict__ means,
                             float* __restrict__ stdev) {
    int b = blockIdx.y;
    int n = blockIdx.x * 256 + threadIdx.x;
    if (n >= Nn) return;
    const float* p = x + (size_t)b * Sn * Nn + n;
    float s = 0.f, s2 = 0.f;
    for (int ss = 0; ss < Sn; ++ss) { float v = p[(size_t)ss * Nn]; s += v; s2 += v * v; }
    float mu = s * (1.0f / Sn);
    float var = s2 * (1.0f / Sn) - mu * mu;
    means[b * Nn + n] = mu;
    stdev[b * Nn + n] = sqrtf(var + 1e-5f);
}

// ---------- xT[b,n,s] = (x[b,s,n]-mu)/sd  (bf16 out) ----------
__global__ void transpose_norm_kernel(const float* __restrict__ x,
                                      const float* __restrict__ means,
                                      const float* __restrict__ stdev,
                                      bf16* __restrict__ xT) {
    __shared__ float tile[32][33];
    int b = blockIdx.z;
    int s0 = blockIdx.x * 32, n0 = blockIdx.y * 32;
    int tx = threadIdx.x, ty = threadIdx.y; // 32 x 8
#pragma unroll
    for (int u = 0; u < 4; ++u) {
        int srow = ty + u * 8;
        int n = n0 + tx;
        tile[srow][tx] = (n < Nn) ? x[((size_t)b * Sn + (s0 + srow)) * Nn + n] : 0.f;
    }
    __syncthreads();
#pragma unroll
    for (int u = 0; u < 4; ++u) {
        int n = n0 + ty + u * 8;
        int s = s0 + tx;
        if (n < Nn) {
            float mu = means[b * Nn + n], sd = stdev[b * Nn + n];
            xT[((size_t)b * Nn + n) * Sn + s] = __float2bfloat16((tile[tx][ty + u * 8] - mu) / sd);
        }
    }
}

// ---------- bf16 MFMA GEMM (m97 structure): C[i,j] = sum_k A[i,k]*B[j,k] ----------
// global_load_lds(16B) staging into unpadded [128][32] LDS, XOR-swizzled.
// batch/split-K both via: zi=z%innerB, zo=z/innerB, base += zi*s?i + zo*s?o.
template <int OUT, int EPI>
__global__ __launch_bounds__(256) void mm_kernel(
    const bf16* __restrict__ A, const bf16* __restrict__ Bm,
    const float* __restrict__ bias, void* __restrict__ C,
    int Mdim, int Ndim, int Kdim, int lda, int ldb, int ldc,
    long sAi, long sAo, long sBi, long sBo, long sCi, long sCo, int innerB) {
    int z = blockIdx.z;
    int zi = z % innerB, zo = z / innerB;
    const bf16* Ab = A + (size_t)zi * sAi + (size_t)zo * sAo;
    const bf16* Bb = Bm + (size_t)zi * sBi + (size_t)zo * sBo;
    __shared__ __align__(16) bf16 As[128 * 32];
    __shared__ __align__(16) bf16 Bs[128 * 32];
    int t = threadIdx.x;
    int wave = t >> 6, lane = t & 63;
    int wr = wave >> 1, wc = wave & 1;
    int q = lane >> 4, l16 = lane & 15;
    int i0 = blockIdx.y * 128, j0 = blockIdx.x * 128;

    int srow0 = t >> 2;              // + u*64
    int scol = (t & 3) * 8;          // LDS col base (element units)
    f32x4 acc[4][4] = {};

    for (int k0 = 0; k0 < Kdim; k0 += 32) {
#pragma unroll
        for (int u = 0; u < 2; ++u) {
            int row = u * 64 + srow0;
            int gcol = scol ^ (((row >> 1) & 3) << 3);   // global col for this LDS slot
            int gi = i0 + row; if (gi >= Mdim) gi = Mdim - 1;
            gld16(Ab + (size_t)gi * lda + k0 + gcol, &As[u * 2048 + wave * 512]);
            int gj = j0 + row; if (gj >= Ndim) gj = Ndim - 1;
            gld16(Bb + (size_t)gj * ldb + k0 + gcol, &Bs[u * 2048 + wave * 512]);
        }
        __syncthreads();
        bf16x8 af[4], bfr[4];
#pragma unroll
        for (int mi = 0; mi < 4; ++mi) {
            int r = wr * 64 + mi * 16 + l16;
            int cl = (q * 8) ^ (((r >> 1) & 3) << 3);
            af[mi] = *reinterpret_cast<const bf16x8*>(&As[r * 32 + cl]);
        }
#pragma unroll
        for (int ni = 0; ni < 4; ++ni) {
            int r = wc * 64 + ni * 16 + l16;
            int cl = (q * 8) ^ (((r >> 1) & 3) << 3);
            bfr[ni] = *reinterpret_cast<const bf16x8*>(&Bs[r * 32 + cl]);
        }
#pragma unroll
        for (int mi = 0; mi < 4; ++mi)
#pragma unroll
            for (int ni = 0; ni < 4; ++ni)
                acc[mi][ni] = __builtin_amdgcn_mfma_f32_16x16x32_bf16(af[mi], bfr[ni], acc[mi][ni], 0, 0, 0);
        __syncthreads();
    }
    size_t cbase = (size_t)zi * sCi + (size_t)zo * sCo;
#pragma unroll
    for (int mi = 0; mi < 4; ++mi) {
#pragma unroll
        for (int r = 0; r < 4; ++r) {
            int gi = i0 + wr * 64 + mi * 16 + q * 4 + r;
            if (gi >= Mdim) continue;
#pragma unroll
            for (int ni = 0; ni < 4; ++ni) {
                int gj = j0 + wc * 64 + ni * 16 + l16;
                if (gj >= Ndim) continue;
                float v = acc[mi][ni][r];
                if (bias) v += bias[gj];
                if (EPI == 1) v = gelu_exact(v);
                size_t cidx = cbase + (size_t)gi * ldc + gj;
                if (OUT == 0) ((float*)C)[cidx] = v;
                else ((bf16*)C)[cidx] = __float2bfloat16(v);
            }
        }
    }
}

// ---------- SWT decomposition: h(b,n,:) fp32 -> coeffs(b,n,4,:) bf16 ----------
__global__ __launch_bounds__(128) void swt_dec_kernel(
    const float* __restrict__ h, const float* __restrict__ h0f,
    const float* __restrict__ h1f, bf16* __restrict__ coeffs) {
    __shared__ float a[2][512];
    int b = blockIdx.y, n = blockIdx.x, t = threadIdx.x;
    const float* hrow = h + ((size_t)b * Nn + n) * Dn;
#pragma unroll
    for (int u = 0; u < 4; ++u) a[0][t + u * 128] = hrow[t + u * 128];
    float f0[3], f1[3];
#pragma unroll
    for (int k = 0; k < 3; ++k) { f0[k] = h0f[n * 3 + k]; f1[k] = h1f[n * 3 + k]; }
    __syncthreads();
    bf16* cb = coeffs + ((size_t)b * Nn + n) * 4 * Dn;
    int cur = 0;
    for (int lev = 0; lev < 3; ++lev) {
        int dil = 1 << lev;
        int pl = 2 * dil - (3 * dil) / 2; // 1,1,2
#pragma unroll
        for (int u = 0; u < 4; ++u) {
            int d = t + u * 128;
            float dv = 0.f, av = 0.f;
#pragma unroll
            for (int k = 0; k < 3; ++k) {
                int idx = (d + k * dil - pl) & 511;
                float xv = a[cur][idx];
                dv += f1[k] * xv;
                av += f0[k] * xv;
            }
            cb[(size_t)(3 - lev) * Dn + d] = __float2bfloat16(dv);
            a[cur ^ 1][d] = av;
        }
        __syncthreads();
        cur ^= 1;
    }
#pragma unroll
    for (int u = 0; u < 4; ++u) cb[t + u * 128] = __float2bfloat16(a[cur][t + u * 128]);
}

// ---------- SWT reconstruction: attn(b,m,n,:) bf16 -> rec(b,n,:) bf16 ----------
__global__ __launch_bounds__(128) void swt_rec_kernel(
    const bf16* __restrict__ attn, const float* __restrict__ g0f,
    const float* __restrict__ g1f, bf16* __restrict__ rec) {
    __shared__ float a[2][512];
    __shared__ float det[512];
    int b = blockIdx.y, n = blockIdx.x, t = threadIdx.x;
    const bf16* base = attn + ((size_t)(b * 4) * Nn + n) * Dn;
#pragma unroll
    for (int u = 0; u < 4; ++u) a[0][t + u * 128] = __bfloat162float(base[t + u * 128]);
    float w0[3], w1[3];
#pragma unroll
    for (int k = 0; k < 3; ++k) { w0[k] = g0f[n * 3 + k]; w1[k] = g1f[n * 3 + k]; }
    int cur = 0;
    for (int i = 0; i < 3; ++i) {
        int dil = 4 >> i;
        int pl = (3 * dil) / 2; // 6,3,1
        const bf16* drow = base + (size_t)(1 + i) * Nn * Dn;
#pragma unroll
        for (int u = 0; u < 4; ++u) det[t + u * 128] = __bfloat162float(drow[t + u * 128]);
        __syncthreads();
#pragma unroll
        for (int u = 0; u < 4; ++u) {
            int d = t + u * 128;
            float s = 0.f;
#pragma unroll
            for (int k = 0; k < 3; ++k) {
                int idx = (d + k * dil - pl) & 511;
                s += w0[k] * a[cur][idx] + w1[k] * det[idx];
            }
            a[cur ^ 1][d] = s * 0.5f;
        }
        __syncthreads();
        cur ^= 1;
    }
    bf16* out = rec + ((size_t)b * Nn + n) * Dn;
#pragma unroll
    for (int u = 0; u < 4; ++u) out[t + u * 128] = __float2bfloat16(a[cur][t + u * 128]);
}

// ---------- fused transpose-convert for QK: (b,n,m,[qk]e) -> (qk,b,m,e,n-pad) ----------
__global__ void tconv2_kernel(const bf16* __restrict__ QK, bf16* __restrict__ QtKt) {
    __shared__ bf16 tile[32][33];
    int zz = blockIdx.z;           // 0..127
    int qk = zz >> 6, bm = zz & 63;
    int b = bm >> 2, m = bm & 3;
    int e0 = blockIdx.x * 32, n0 = blockIdx.y * 32;
    int tx = threadIdx.x, ty = threadIdx.y; // 32 x 8
    const bf16* ib = QK + (size_t)b * Nn * 4096 + (size_t)m * 1024 + (size_t)qk * 512;
    bf16* ob = QtKt + (size_t)qk * 64 * 512 * KP + (size_t)bm * 512 * KP;
#pragma unroll
    for (int u = 0; u < 4; ++u) {
        int n = n0 + ty + u * 8;
        bf16 v = __float2bfloat16(0.f);
        if (n < Nn) v = ib[(size_t)n * 4096 + e0 + tx];
        tile[ty + u * 8][tx] = v;
    }
    __syncthreads();
#pragma unroll
    for (int u = 0; u < 4; ++u) {
        int e = e0 + ty + u * 8;
        int n = n0 + tx;
        if (n < KP) ob[(size_t)e * KP + n] = tile[tx][ty + u * 8];
    }
}

// ---------- fused column sum-sq for QK: outv[qk][bm][e] ----------
__global__ __launch_bounds__(256) void colsq2_kernel(const bf16* __restrict__ QK,
                                                     float* __restrict__ outv) {
    int y = blockIdx.y;            // 0..127
    int qk = y >> 6, bm = y & 63;
    int b = bm >> 2, m = bm & 3;
    int e0 = blockIdx.x * 64;
    int tx = threadIdx.x & 63, ty = threadIdx.x >> 6;
    const bf16* base = QK + ((size_t)b * Nn * 4 + m) * 1024 + (size_t)qk * 512;
    float s = 0.f;
    for (int n = ty; n < Nn; n += 4) {
        float v = __bfloat162float(base[(size_t)n * 4096 + e0 + tx]);
        s += v * v;
    }
    __shared__ float red[4][64];
    red[ty][tx] = s;
    __syncthreads();
    if (ty == 0)
        outv[(size_t)qk * 32768 + (size_t)bm * 512 + e0 + tx] =
            red[0][tx] + red[1][tx] + red[2][tx] + red[3][tx];
}

// ---------- geometric scores + softmax, IN PLACE on bf16 Smat[bm,l,s] ----------
__global__ __launch_bounds__(256) void wedge_softmax_kernel(
    bf16* __restrict__ Smat, const float* __restrict__ qn2, const float* __restrict__ kn2) {
    int bm = blockIdx.y, l = blockIdx.x, t = threadIdx.x;
    bf16* row = Smat + ((size_t)bm * 512 + l) * 512;
    const float* kn = kn2 + (size_t)bm * 512;
    float q2 = qn2[(size_t)bm * 512 + l];
    const float scale = rsqrtf(321.0f);
    float v[2];
    float mx = -1e30f;
#pragma unroll
    for (int u = 0; u < 2; ++u) {
        int s = t + u * 256;
        float d = __bfloat162float(row[s]);
        float w = sqrtf(fmaxf(q2 * kn[s] - d * d, 0.f) + 1e-8f);
        float sc = (0.7f * d + 0.3f * w) * scale;
        v[u] = sc;
        mx = fmaxf(mx, sc);
    }
    __shared__ float red[256];
    red[t] = mx;
    __syncthreads();
    for (int o = 128; o > 0; o >>= 1) {
        if (t < o) red[t] = fmaxf(red[t], red[t + o]);
        __syncthreads();
    }
    mx = red[0];
    __syncthreads();
    float sum = 0.f;
#pragma unroll
    for (int u = 0; u < 2; ++u) {
        v[u] = expf(v[u] - mx);
        sum += v[u];
    }
    red[t] = sum;
    __syncthreads();
    for (int o = 128; o > 0; o >>= 1) {
        if (t < o) red[t] += red[t + o];
        __syncthreads();
    }
    float inv = 1.0f / red[0];
#pragma unroll
    for (int u = 0; u < 2; ++u) row[t + u * 256] = __float2bfloat16(v[u] * inv);
}

// ---------- LayerNorm over D of (A [+ R] [+ R2]); fp32 and/or bf16 out ----------
__global__ __launch_bounds__(128) void ln_kernel(
    const float* __restrict__ A, const float* __restrict__ R, const float* __restrict__ R2,
    const float* __restrict__ g, const float* __restrict__ bb,
    float* __restrict__ outf, bf16* __restrict__ outb) {
    size_t r = blockIdx.x;
    int t = threadIdx.x;
    const float* ra = A + r * Dn;
    float x[4];
    float s = 0.f, s2 = 0.f;
#pragma unroll
    for (int u = 0; u < 4; ++u) {
        int d = t + u * 128;
        float v = ra[d];
        if (R) v += R[r * Dn + d];
        if (R2) v += R2[r * Dn + d];
        x[u] = v;
        s += v;
        s2 += v * v;
    }
    __shared__ float rs[128], rs2[128];
    rs[t] = s;
    rs2[t] = s2;
    __syncthreads();
    for (int o = 64; o > 0; o >>= 1) {
        if (t < o) { rs[t] += rs[t + o]; rs2[t] += rs2[t + o]; }
        __syncthreads();
    }
    float mean = rs[0] * (1.0f / Dn);
    float var = rs2[0] * (1.0f / Dn) - mean * mean;
    float inv = rsqrtf(var + 1e-5f);
#pragma unroll
    for (int u = 0; u < 4; ++u) {
        int d = t + u * 128;
        float v = (x[u] - mean) * inv * g[d] + bb[d];
        if (outf) outf[r * Dn + d] = v;
        if (outb) outb[r * Dn + d] = __float2bfloat16(v);
    }
}

// ---------- dec[b,p,n] = (sum of 4 split-K partials)*sd + mu ----------
__global__ void out_scale_kernel(const float* __restrict__ ptmp,
                                 const float* __restrict__ means,
                                 const float* __restrict__ stdev, float* __restrict__ dec) {
    int idx = blockIdx.x * 256 + threadIdx.x;
    if (idx >= Bn * Pn * Nn) return;
    int n = idx % Nn;
    int bp = idx / Nn;
    int p = bp % Pn;
    int b = bp / Pn;
    const size_t PS = (size_t)Bn * Nn * Pn;
    size_t base = ((size_t)b * Nn + n) * Pn + p;
    float v = ptmp[base] + ptmp[base + PS] + ptmp[base + 2 * PS] + ptmp[base + 3 * PS];
    dec[idx] = v * stdev[b * Nn + n] + means[b * Nn + n];
}

extern "C" void kernel_launch(void* const* d_in, const int* in_sizes, int n_in,
                              void* d_out, int out_size, void* d_ws, size_t ws_size,
                              hipStream_t stream) {
    const float* x_enc = (const float*)d_in[0];
    const float* emb_W = (const float*)d_in[1];
    const float* emb_b = (const float*)d_in[2];
    const float* h0 = (const float*)d_in[3];
    const float* h1 = (const float*)d_in[4];
    const float* g0 = (const float*)d_in[5];
    const float* g1 = (const float*)d_in[6];
    const float* Wq = (const float*)d_in[7];
    const float* bq = (const float*)d_in[8];
    const float* Wk = (const float*)d_in[9];
    const float* bk = (const float*)d_in[10];
    const float* Wv = (const float*)d_in[11];
    const float* bv = (const float*)d_in[12];
    const float* Wo = (const float*)d_in[13];
    const float* bo = (const float*)d_in[14];
    const float* W1 = (const float*)d_in[15];
    const float* b1 = (const float*)d_in[16];
    const float* W2 = (const float*)d_in[17];
    const float* b2 = (const float*)d_in[18];
    const float* ln1_g = (const float*)d_in[19];
    const float* ln1_b = (const float*)d_in[20];
    const float* ln2_g = (const float*)d_in[21];
    const float* ln2_b = (const float*)d_in[22];
    const float* lnf_g = (const float*)d_in[23];
    const float* lnf_b = (const float*)d_in[24];
    const float* proj_W = (const float*)d_in[25];
    const float* proj_b = (const float*)d_in[26];

    float* dec = (float*)d_out;
    float* means = dec + (size_t)Bn * Pn * Nn;
    float* stdev = means + (size_t)Bn * Nn;

    // ---- workspace carve (~154 MB, round-6-proven watermark) ----
    char* p = (char*)d_ws;
    auto alloc = [&](size_t bytes) { char* r = p; p += (bytes + 255) & ~(size_t)255; return r; };
    const size_t RD = (size_t)Bn * Nn * Dn;        // 2,629,632 elements
    const size_t RQ4 = RD * 4;                     // 10,518,528

    bf16* embWb = (bf16*)alloc(262144 * 2);
    bf16* Wqkb = (bf16*)alloc(2 * 524288 * 2);     // per layer: [Wq;Wk] rows, 1024x512
    bf16* Wvb = (bf16*)alloc(2 * 262144 * 2);
    bf16* Wob = (bf16*)alloc(2 * 262144 * 2);
    bf16* W1b = (bf16*)alloc(2 * 1048576 * 2);
    bf16* W2b = (bf16*)alloc(2 * 1048576 * 2);
    bf16* projWb = (bf16*)alloc(49152 * 2);
    float* bqk = (float*)alloc(2048 * 4);

    float* hbuf = (float*)alloc(RD * 4);
    char* regC = alloc(RQ4 * 2);                     // coeffs_b | attn_b
    char* regQ = alloc(RQ4 * 2);                     // QK0b(head) | Smat(head) | recb,x1b | ptmp
    char* regK = alloc(RQ4 * 2);                     // QK0b(tail) | Smat(tail)
    char* regV = alloc(RQ4 * 2);                     // V0b | yb
    char* regT = alloc((size_t)2 * 64 * 512 * KP * 2); // xT_b | QtKt | x1,tmp(x2),hfb
    float* qn2 = (float*)alloc((size_t)2 * 64 * 512 * 4);
    float* kn2 = qn2 + 32768;

    bf16* coeffs_b = (bf16*)regC;
    bf16* attn_b = (bf16*)regC;
    bf16* QK0b = (bf16*)regQ;                        // 20544 x 1024 bf16 = regQ+regK exactly
    bf16* Smat = (bf16*)regQ;                        // 64*512*512 bf16, spans regQ+regK
    bf16* recb = (bf16*)regQ;                        // after Smat dead
    bf16* x1b = (bf16*)(regQ + RD * 2);
    float* ptmp = (float*)regQ;                      // 4 partials x R*Pn fp32 = 7.9 MB
    bf16* V0b = (bf16*)regV;
    bf16* yb = (bf16*)regV;
    bf16* QtKt = (bf16*)regT;                        // Qt | Kt, each 64*512*KP
    bf16* Qt = QtKt;
    bf16* Kt = QtKt + (size_t)64 * 512 * KP;
    bf16* xT_b = (bf16*)regT;                        // dead before QtKt written
    float* x1 = (float*)regT;
    float* tmp = (float*)(regT + RD * 4);            // 2 split-K partials (21 MB)
    bf16* hfb = (bf16*)(regT + RD * 12);

    const int R = Bn * Nn;   // 5136
    const int RQr = R * 4;   // 20544
    const long sbm = (long)4 * Nn * 512;      // per-b stride in V0b/attn
    const long sS = (long)512 * 512;
    const long sTq = (long)512 * KP;          // per-m stride in Qt/Kt
    const long sTb = 4 * sTq;                 // per-b stride in Qt/Kt

    // ---- fused weight conversion (1 launch); Wq/Wk interleave into Wqkb ----
    CvtPack cp;
    int ci = 0;
    auto addcvt = [&](const float* s, bf16* d, int n) { cp.src[ci] = s; cp.dst[ci] = d; cp.cnt[ci] = n; ++ci; };
    addcvt(emb_W, embWb, 262144);
    for (int l = 0; l < 2; ++l) {
        addcvt(Wq + (size_t)l * 262144, Wqkb + (size_t)l * 524288, 262144);
        addcvt(Wk + (size_t)l * 262144, Wqkb + (size_t)l * 524288 + 262144, 262144);
        addcvt(Wv + (size_t)l * 262144, Wvb + (size_t)l * 262144, 262144);
        addcvt(Wo + (size_t)l * 262144, Wob + (size_t)l * 262144, 262144);
        addcvt(W1 + (size_t)l * 1048576, W1b + (size_t)l * 1048576, 1048576);
        addcvt(W2 + (size_t)l * 1048576, W2b + (size_t)l * 1048576, 1048576);
    }
    addcvt(proj_W, projWb, 49152);
    cvt_all_kernel<<<dim3(1048576 / 4 / 256, 14), 256, 0, stream>>>(cp);
    bias_pack_kernel<<<8, 256, 0, stream>>>(bq, bk, bqk);

    stats_kernel<<<dim3((Nn + 255) / 256, Bn), 256, 0, stream>>>(x_enc, means, stdev);
    transpose_norm_kernel<<<dim3(Sn / 32, (Nn + 31) / 32, Bn), dim3(32, 8), 0, stream>>>(
        x_enc, means, stdev, xT_b);

    // h = xT(5136x512) * emb_W^T + emb_b  -> fp32
    mm_kernel<0, 0><<<dim3(4, (R + 127) / 128, 1), 256, 0, stream>>>(
        xT_b, embWb, emb_b, hbuf, R, Dn, Sn, Sn, Sn, Dn, 0, 0, 0, 0, 0, 0, 1);

    for (int l = 0; l < 2; ++l) {
        const float* h0l = h0 + (size_t)l * Nn * 3;
        const float* h1l = h1 + (size_t)l * Nn * 3;
        const float* g0l = g0 + (size_t)l * Nn * 3;
        const float* g1l = g1 + (size_t)l * Nn * 3;

        swt_dec_kernel<<<dim3(Nn, Bn), 128, 0, stream>>>(hbuf, h0l, h1l, coeffs_b);

        // fused QK: rows (b,n,m) x 1024 -> QK0b (1288 blocks)
        mm_kernel<1, 0><<<dim3(8, (RQr + 127) / 128, 1), 256, 0, stream>>>(
            coeffs_b, Wqkb + (size_t)l * 524288, bqk + (size_t)l * 1024, QK0b,
            RQr, 1024, Dn, Dn, Dn, 1024, 0, 0, 0, 0, 0, 0, 1);
        // V: rows (b,n,m) x 512 -> V0b
        mm_kernel<1, 0><<<dim3(4, (RQr + 127) / 128, 1), 256, 0, stream>>>(
            coeffs_b, Wvb + (size_t)l * 262144, bv + (size_t)l * Dn, V0b,
            RQr, Dn, Dn, Dn, Dn, Dn, 0, 0, 0, 0, 0, 0, 1);

        colsq2_kernel<<<dim3(8, 128), 256, 0, stream>>>(QK0b, qn2);
        tconv2_kernel<<<dim3(16, 11, 128), dim3(32, 8), 0, stream>>>(QK0b, QtKt);

        // dot[bm,l,s] = sum_n Qt[l,n]*Kt[s,n] -> bf16 Smat (QK0b dead now)
        mm_kernel<1, 0><<<dim3(4, 4, 64), 256, 0, stream>>>(
            Qt, Kt, nullptr, Smat, 512, 512, KP, KP, KP, 512,
            sTq, sTb, sTq, sTb, sS, 4 * sS, 4);

        wedge_softmax_kernel<<<dim3(512, 64), 256, 0, stream>>>(Smat, qn2, kn2);

        // attn[b,m,n,l] = sum_s V0b[(b,n,m),s] * Smat[bm,l,s] -> bf16
        mm_kernel<1, 0><<<dim3(4, (Nn + 127) / 128, 64), 256, 0, stream>>>(
            V0b, Smat, nullptr, attn_b, Nn, 512, 512, 2048, 512, 512,
            512, sbm, sS, 4 * sS, (long)Nn * 512, (long)4 * Nn * 512, 4);

        // Smat dead; recb overwrites its head
        swt_rec_kernel<<<dim3(Nn, Bn), 128, 0, stream>>>(attn_b, g0l, g1l, recb);

        // Wo split-K=2 -> tmp partials (328 blocks)
        mm_kernel<0, 0><<<dim3(4, (R + 127) / 128, 2), 256, 0, stream>>>(
            recb, Wob + (size_t)l * 262144, bo + (size_t)l * Dn, tmp,
            R, Dn, 256, Dn, Dn, Dn, 256, 0, 256, 0, (long)RD, 0, 2);
        ln_kernel<<<R, 128, 0, stream>>>(hbuf, tmp, tmp + RD, ln1_g + (size_t)l * Dn,
                                         ln1_b + (size_t)l * Dn, x1, x1b);

        // FFN1 (gelu, bf16 out)
        mm_kernel<1, 1><<<dim3(16, (R + 127) / 128, 1), 256, 0, stream>>>(
            x1b, W1b + (size_t)l * 1048576, b1 + (size_t)l * DFn, yb,
            R, DFn, Dn, Dn, Dn, DFn, 0, 0, 0, 0, 0, 0, 1);
        // FFN2 split-K=2 -> tmp partials (328 blocks)
        mm_kernel<0, 0><<<dim3(4, (R + 127) / 128, 2), 256, 0, stream>>>(
            yb, W2b + (size_t)l * 1048576, b2 + (size_t)l * Dn, tmp,
            R, Dn, 1024, DFn, DFn, Dn, 1024, 0, 1024, 0, (long)RD, 0, 2);
        ln_kernel<<<R, 128, 0, stream>>>(x1, tmp, tmp + RD, ln2_g + (size_t)l * Dn,
                                         ln2_b + (size_t)l * Dn, hbuf, nullptr);
    }

    ln_kernel<<<R, 128, 0, stream>>>(hbuf, nullptr, nullptr, lnf_g, lnf_b, nullptr, hfb);
    // proj split-K=4 -> ptmp partials (164 blocks)
    mm_kernel<0, 0><<<dim3(1, (R + 127) / 128, 4), 256, 0, stream>>>(
        hfb, projWb, proj_b, ptmp, R, Pn, 128, Dn, Dn, Pn,
        128, 0, 128, 0, (long)R * Pn, 0, 4);
    out_scale_kernel<<<(Bn * Pn * Nn + 255) / 256, 256, 0, stream>>>(ptmp, means, stdev, dec);
}

// Round 8
// 914.831 us; speedup vs baseline: 6.0818x; 1.0961x over previous
//
#include <hip/hip_runtime.h>
#include <hip/hip_bf16.h>
#include <math.h>
#include <stdint.h>

#define Bn 16
#define Sn 512
#define Nn 321
#define Dn 512
#define DFn 2048
#define Pn 96
#define KP 352   // Nn padded to multiple of 32

typedef __bf16 bf16x8 __attribute__((ext_vector_type(8)));
typedef float f32x4 __attribute__((ext_vector_type(4)));
typedef __hip_bfloat16 bf16;

static __device__ __forceinline__ float gelu_exact(float x) {
    return 0.5f * x * (1.0f + erff(x * 0.7071067811865476f));
}

static __device__ __forceinline__ void gld16(const void* g, void* l) {
    __builtin_amdgcn_global_load_lds(
        (const __attribute__((address_space(1))) void*)(uintptr_t)g,
        (__attribute__((address_space(3))) void*)(uintptr_t)l, 16, 0, 0);
}

// ---------- fused fp32 -> bf16 weight conversion (single launch) ----------
struct CvtPack {
    const float* src[14];
    bf16* dst[14];
    int cnt[14];
};
__global__ void cvt_all_kernel(CvtPack p) {
    int seg = blockIdx.y;
    int n = p.cnt[seg];
    const float* s = p.src[seg];
    bf16* d = p.dst[seg];
    int i = (blockIdx.x * 256 + threadIdx.x) * 4;
    if (i + 3 < n) {
        float4 v = *reinterpret_cast<const float4*>(s + i);
        d[i] = __float2bfloat16(v.x);
        d[i + 1] = __float2bfloat16(v.y);
        d[i + 2] = __float2bfloat16(v.z);
        d[i + 3] = __float2bfloat16(v.w);
    }
}

// ---------- combined QK bias ----------
__global__ void bias_pack_kernel(const float* __restrict__ bq, const float* __restrict__ bk,
                                 float* __restrict__ bqk) {
    int idx = blockIdx.x * 256 + threadIdx.x;
    if (idx >= 2048) return;
    int l = idx >> 10, j = idx & 1023;
    bqk[idx] = (j < 512) ? bq[l * 512 + j] : bk[l * 512 + j - 512];
}

// ---------- per-(b,n) mean/std over S ----------
__global__ void stats_kernel(const float* __restrict__ x, float* __restrict__ means,
                             float* __restrict__ stdev) {
    int b = blockIdx.y;
    int n = blockIdx.x * 256 + threadIdx.x;
    if (n >= Nn) return;
    const float* p = x + (size_t)b * Sn * Nn + n;
    float s = 0.f, s2 = 0.f;
    for (int ss = 0; ss < Sn; ++ss) { float v = p[(size_t)ss * Nn]; s += v; s2 += v * v; }
    float mu = s * (1.0f / Sn);
    float var = s2 * (1.0f / Sn) - mu * mu;
    means[b * Nn + n] = mu;
    stdev[b * Nn + n] = sqrtf(var + 1e-5f);
}

// ---------- xT[b,n,s] = (x[b,s,n]-mu)/sd  (bf16 out) ----------
__global__ void transpose_norm_kernel(const float* __restrict__ x,
                                      const float* __restrict__ means,
                                      const float* __restrict__ stdev,
                                      bf16* __restrict__ xT) {
    __shared__ float tile[32][33];
    int b = blockIdx.z;
    int s0 = blockIdx.x * 32, n0 = blockIdx.y * 32;
    int tx = threadIdx.x, ty = threadIdx.y; // 32 x 8
#pragma unroll
    for (int u = 0; u < 4; ++u) {
        int srow = ty + u * 8;
        int n = n0 + tx;
        tile[srow][tx] = (n < Nn) ? x[((size_t)b * Sn + (s0 + srow)) * Nn + n] : 0.f;
    }
    __syncthreads();
#pragma unroll
    for (int u = 0; u < 4; ++u) {
        int n = n0 + ty + u * 8;
        int s = s0 + tx;
        if (n < Nn) {
            float mu = means[b * Nn + n], sd = stdev[b * Nn + n];
            xT[((size_t)b * Nn + n) * Sn + s] = __float2bfloat16((tile[tx][ty + u * 8] - mu) / sd);
        }
    }
}

// ---------- bf16 MFMA GEMM: double-buffered global_load_lds + XCD swizzle ----------
// C[i,j] = sum_k A[i,k]*B[j,k]; unpadded [128][32] LDS x2 buffers, XOR-swizzled.
template <int OUT, int EPI>
__global__ __launch_bounds__(256) void mm_kernel(
    const bf16* __restrict__ A, const bf16* __restrict__ Bm,
    const float* __restrict__ bias, void* __restrict__ C,
    int Mdim, int Ndim, int Kdim, int lda, int ldb, int ldc,
    long sAi, long sAo, long sBi, long sBo, long sCi, long sCo, int innerB) {
    int z = blockIdx.z;
    int zi = z % innerB, zo = z / innerB;
    const bf16* Ab = A + (size_t)zi * sAi + (size_t)zo * sAo;
    const bf16* Bb = Bm + (size_t)zi * sBi + (size_t)zo * sBo;

    // XCD-grouping swizzle: blocks sharing a C row-tile (same by) get dispatch
    // indices == same (mod 8) -> same XCD L2 caches the shared A row-tile.
    int gx = gridDim.x, gy = gridDim.y;
    int lin = blockIdx.y * gx + blockIdx.x;
    int prefix = (gy & ~7) * gx;
    int bx, by;
    if (lin < prefix) {
        bx = (lin >> 3) % gx;
        by = (lin / (8 * gx)) * 8 + (lin & 7);
    } else {
        int r = lin - prefix;
        bx = r % gx;
        by = (gy & ~7) + r / gx;
    }

    __shared__ __align__(16) bf16 As[2][128 * 32];
    __shared__ __align__(16) bf16 Bs[2][128 * 32];
    int t = threadIdx.x;
    int wave = t >> 6, lane = t & 63;
    int wr = wave >> 1, wc = wave & 1;
    int q = lane >> 4, l16 = lane & 15;
    int i0 = by * 128, j0 = bx * 128;

    int srow0 = t >> 2;              // + u*64
    int scol = (t & 3) * 8;          // LDS col base (element units)
    f32x4 acc[4][4] = {};

    int nIter = Kdim >> 5;

    auto stage = [&](int k0, int buf) {
#pragma unroll
        for (int u = 0; u < 2; ++u) {
            int row = u * 64 + srow0;
            int gcol = scol ^ (((row >> 1) & 3) << 3);
            int gi = i0 + row; if (gi >= Mdim) gi = Mdim - 1;
            gld16(Ab + (size_t)gi * lda + k0 + gcol, &As[buf][u * 2048 + wave * 512]);
            int gj = j0 + row; if (gj >= Ndim) gj = Ndim - 1;
            gld16(Bb + (size_t)gj * ldb + k0 + gcol, &Bs[buf][u * 2048 + wave * 512]);
        }
    };

    stage(0, 0);
    for (int it = 0; it < nIter; ++it) {
        __syncthreads();                       // drains stage(it) loads
        if (it + 1 < nIter) stage((it + 1) << 5, (it + 1) & 1);  // overlaps compute below
        int buf = it & 1;
        bf16x8 af[4], bfr[4];
#pragma unroll
        for (int mi = 0; mi < 4; ++mi) {
            int r = wr * 64 + mi * 16 + l16;
            int cl = (q * 8) ^ (((r >> 1) & 3) << 3);
            af[mi] = *reinterpret_cast<const bf16x8*>(&As[buf][r * 32 + cl]);
        }
#pragma unroll
        for (int ni = 0; ni < 4; ++ni) {
            int r = wc * 64 + ni * 16 + l16;
            int cl = (q * 8) ^ (((r >> 1) & 3) << 3);
            bfr[ni] = *reinterpret_cast<const bf16x8*>(&Bs[buf][r * 32 + cl]);
        }
#pragma unroll
        for (int mi = 0; mi < 4; ++mi)
#pragma unroll
            for (int ni = 0; ni < 4; ++ni)
                acc[mi][ni] = __builtin_amdgcn_mfma_f32_16x16x32_bf16(af[mi], bfr[ni], acc[mi][ni], 0, 0, 0);
    }
    size_t cbase = (size_t)zi * sCi + (size_t)zo * sCo;
#pragma unroll
    for (int mi = 0; mi < 4; ++mi) {
#pragma unroll
        for (int r = 0; r < 4; ++r) {
            int gi = i0 + wr * 64 + mi * 16 + q * 4 + r;
            if (gi >= Mdim) continue;
#pragma unroll
            for (int ni = 0; ni < 4; ++ni) {
                int gj = j0 + wc * 64 + ni * 16 + l16;
                if (gj >= Ndim) continue;
                float v = acc[mi][ni][r];
                if (bias) v += bias[gj];
                if (EPI == 1) v = gelu_exact(v);
                size_t cidx = cbase + (size_t)gi * ldc + gj;
                if (OUT == 0) ((float*)C)[cidx] = v;
                else ((bf16*)C)[cidx] = __float2bfloat16(v);
            }
        }
    }
}

// ---------- SWT decomposition: h(b,n,:) fp32 -> coeffs(b,n,4,:) bf16 ----------
__global__ __launch_bounds__(128) void swt_dec_kernel(
    const float* __restrict__ h, const float* __restrict__ h0f,
    const float* __restrict__ h1f, bf16* __restrict__ coeffs) {
    __shared__ float a[2][512];
    int b = blockIdx.y, n = blockIdx.x, t = threadIdx.x;
    const float* hrow = h + ((size_t)b * Nn + n) * Dn;
#pragma unroll
    for (int u = 0; u < 4; ++u) a[0][t + u * 128] = hrow[t + u * 128];
    float f0[3], f1[3];
#pragma unroll
    for (int k = 0; k < 3; ++k) { f0[k] = h0f[n * 3 + k]; f1[k] = h1f[n * 3 + k]; }
    __syncthreads();
    bf16* cb = coeffs + ((size_t)b * Nn + n) * 4 * Dn;
    int cur = 0;
    for (int lev = 0; lev < 3; ++lev) {
        int dil = 1 << lev;
        int pl = 2 * dil - (3 * dil) / 2; // 1,1,2
#pragma unroll
        for (int u = 0; u < 4; ++u) {
            int d = t + u * 128;
            float dv = 0.f, av = 0.f;
#pragma unroll
            for (int k = 0; k < 3; ++k) {
                int idx = (d + k * dil - pl) & 511;
                float xv = a[cur][idx];
                dv += f1[k] * xv;
                av += f0[k] * xv;
            }
            cb[(size_t)(3 - lev) * Dn + d] = __float2bfloat16(dv);
            a[cur ^ 1][d] = av;
        }
        __syncthreads();
        cur ^= 1;
    }
#pragma unroll
    for (int u = 0; u < 4; ++u) cb[t + u * 128] = __float2bfloat16(a[cur][t + u * 128]);
}

// ---------- SWT reconstruction: attn(b,m,n,:) bf16 -> rec(b,n,:) bf16 ----------
__global__ __launch_bounds__(128) void swt_rec_kernel(
    const bf16* __restrict__ attn, const float* __restrict__ g0f,
    const float* __restrict__ g1f, bf16* __restrict__ rec) {
    __shared__ float a[2][512];
    __shared__ float det[512];
    int b = blockIdx.y, n = blockIdx.x, t = threadIdx.x;
    const bf16* base = attn + ((size_t)(b * 4) * Nn + n) * Dn;
#pragma unroll
    for (int u = 0; u < 4; ++u) a[0][t + u * 128] = __bfloat162float(base[t + u * 128]);
    float w0[3], w1[3];
#pragma unroll
    for (int k = 0; k < 3; ++k) { w0[k] = g0f[n * 3 + k]; w1[k] = g1f[n * 3 + k]; }
    int cur = 0;
    for (int i = 0; i < 3; ++i) {
        int dil = 4 >> i;
        int pl = (3 * dil) / 2; // 6,3,1
        const bf16* drow = base + (size_t)(1 + i) * Nn * Dn;
#pragma unroll
        for (int u = 0; u < 4; ++u) det[t + u * 128] = __bfloat162float(drow[t + u * 128]);
        __syncthreads();
#pragma unroll
        for (int u = 0; u < 4; ++u) {
            int d = t + u * 128;
            float s = 0.f;
#pragma unroll
            for (int k = 0; k < 3; ++k) {
                int idx = (d + k * dil - pl) & 511;
                s += w0[k] * a[cur][idx] + w1[k] * det[idx];
            }
            a[cur ^ 1][d] = s * 0.5f;
        }
        __syncthreads();
        cur ^= 1;
    }
    bf16* out = rec + ((size_t)b * Nn + n) * Dn;
#pragma unroll
    for (int u = 0; u < 4; ++u) out[t + u * 128] = __float2bfloat16(a[cur][t + u * 128]);
}

// ---------- fused transpose-convert for QK: (b,n,m,[qk]e) -> (qk,b,m,e,n-pad) ----------
__global__ void tconv2_kernel(const bf16* __restrict__ QK, bf16* __restrict__ QtKt) {
    __shared__ bf16 tile[32][33];
    int zz = blockIdx.z;           // 0..127
    int qk = zz >> 6, bm = zz & 63;
    int b = bm >> 2, m = bm & 3;
    int e0 = blockIdx.x * 32, n0 = blockIdx.y * 32;
    int tx = threadIdx.x, ty = threadIdx.y; // 32 x 8
    const bf16* ib = QK + (size_t)b * Nn * 4096 + (size_t)m * 1024 + (size_t)qk * 512;
    bf16* ob = QtKt + (size_t)qk * 64 * 512 * KP + (size_t)bm * 512 * KP;
#pragma unroll
    for (int u = 0; u < 4; ++u) {
        int n = n0 + ty + u * 8;
        bf16 v = __float2bfloat16(0.f);
        if (n < Nn) v = ib[(size_t)n * 4096 + e0 + tx];
        tile[ty + u * 8][tx] = v;
    }
    __syncthreads();
#pragma unroll
    for (int u = 0; u < 4; ++u) {
        int e = e0 + ty + u * 8;
        int n = n0 + tx;
        if (n < KP) ob[(size_t)e * KP + n] = tile[tx][ty + u * 8];
    }
}

// ---------- fused column sum-sq for QK: outv[qk][bm][e] ----------
__global__ __launch_bounds__(256) void colsq2_kernel(const bf16* __restrict__ QK,
                                                     float* __restrict__ outv) {
    int y = blockIdx.y;            // 0..127
    int qk = y >> 6, bm = y & 63;
    int b = bm >> 2, m = bm & 3;
    int e0 = blockIdx.x * 64;
    int tx = threadIdx.x & 63, ty = threadIdx.x >> 6;
    const bf16* base = QK + ((size_t)b * Nn * 4 + m) * 1024 + (size_t)qk * 512;
    float s = 0.f;
    for (int n = ty; n < Nn; n += 4) {
        float v = __bfloat162float(base[(size_t)n * 4096 + e0 + tx]);
        s += v * v;
    }
    __shared__ float red[4][64];
    red[ty][tx] = s;
    __syncthreads();
    if (ty == 0)
        outv[(size_t)qk * 32768 + (size_t)bm * 512 + e0 + tx] =
            red[0][tx] + red[1][tx] + red[2][tx] + red[3][tx];
}

// ---------- geometric scores + softmax, IN PLACE on bf16 Smat[bm,l,s] ----------
__global__ __launch_bounds__(256) void wedge_softmax_kernel(
    bf16* __restrict__ Smat, const float* __restrict__ qn2, const float* __restrict__ kn2) {
    int bm = blockIdx.y, l = blockIdx.x, t = threadIdx.x;
    bf16* row = Smat + ((size_t)bm * 512 + l) * 512;
    const float* kn = kn2 + (size_t)bm * 512;
    float q2 = qn2[(size_t)bm * 512 + l];
    const float scale = rsqrtf(321.0f);
    float v[2];
    float mx = -1e30f;
#pragma unroll
    for (int u = 0; u < 2; ++u) {
        int s = t + u * 256;
        float d = __bfloat162float(row[s]);
        float w = sqrtf(fmaxf(q2 * kn[s] - d * d, 0.f) + 1e-8f);
        float sc = (0.7f * d + 0.3f * w) * scale;
        v[u] = sc;
        mx = fmaxf(mx, sc);
    }
    __shared__ float red[256];
    red[t] = mx;
    __syncthreads();
    for (int o = 128; o > 0; o >>= 1) {
        if (t < o) red[t] = fmaxf(red[t], red[t + o]);
        __syncthreads();
    }
    mx = red[0];
    __syncthreads();
    float sum = 0.f;
#pragma unroll
    for (int u = 0; u < 2; ++u) {
        v[u] = expf(v[u] - mx);
        sum += v[u];
    }
    red[t] = sum;
    __syncthreads();
    for (int o = 128; o > 0; o >>= 1) {
        if (t < o) red[t] += red[t + o];
        __syncthreads();
    }
    float inv = 1.0f / red[0];
#pragma unroll
    for (int u = 0; u < 2; ++u) row[t + u * 256] = __float2bfloat16(v[u] * inv);
}

// ---------- LayerNorm over D of (A [+ R] [+ R2]); fp32 and/or bf16 out ----------
__global__ __launch_bounds__(128) void ln_kernel(
    const float* __restrict__ A, const float* __restrict__ R, const float* __restrict__ R2,
    const float* __restrict__ g, const float* __restrict__ bb,
    float* __restrict__ outf, bf16* __restrict__ outb) {
    size_t r = blockIdx.x;
    int t = threadIdx.x;
    const float* ra = A + r * Dn;
    float x[4];
    float s = 0.f, s2 = 0.f;
#pragma unroll
    for (int u = 0; u < 4; ++u) {
        int d = t + u * 128;
        float v = ra[d];
        if (R) v += R[r * Dn + d];
        if (R2) v += R2[r * Dn + d];
        x[u] = v;
        s += v;
        s2 += v * v;
    }
    __shared__ float rs[128], rs2[128];
    rs[t] = s;
    rs2[t] = s2;
    __syncthreads();
    for (int o = 64; o > 0; o >>= 1) {
        if (t < o) { rs[t] += rs[t + o]; rs2[t] += rs2[t + o]; }
        __syncthreads();
    }
    float mean = rs[0] * (1.0f / Dn);
    float var = rs2[0] * (1.0f / Dn) - mean * mean;
    float inv = rsqrtf(var + 1e-5f);
#pragma unroll
    for (int u = 0; u < 4; ++u) {
        int d = t + u * 128;
        float v = (x[u] - mean) * inv * g[d] + bb[d];
        if (outf) outf[r * Dn + d] = v;
        if (outb) outb[r * Dn + d] = __float2bfloat16(v);
    }
}

// ---------- dec[b,p,n] = (sum of 4 split-K partials)*sd + mu ----------
__global__ void out_scale_kernel(const float* __restrict__ ptmp,
                                 const float* __restrict__ means,
                                 const float* __restrict__ stdev, float* __restrict__ dec) {
    int idx = blockIdx.x * 256 + threadIdx.x;
    if (idx >= Bn * Pn * Nn) return;
    int n = idx % Nn;
    int bp = idx / Nn;
    int p = bp % Pn;
    int b = bp / Pn;
    const size_t PS = (size_t)Bn * Nn * Pn;
    size_t base = ((size_t)b * Nn + n) * Pn + p;
    float v = ptmp[base] + ptmp[base + PS] + ptmp[base + 2 * PS] + ptmp[base + 3 * PS];
    dec[idx] = v * stdev[b * Nn + n] + means[b * Nn + n];
}

extern "C" void kernel_launch(void* const* d_in, const int* in_sizes, int n_in,
                              void* d_out, int out_size, void* d_ws, size_t ws_size,
                              hipStream_t stream) {
    const float* x_enc = (const float*)d_in[0];
    const float* emb_W = (const float*)d_in[1];
    const float* emb_b = (const float*)d_in[2];
    const float* h0 = (const float*)d_in[3];
    const float* h1 = (const float*)d_in[4];
    const float* g0 = (const float*)d_in[5];
    const float* g1 = (const float*)d_in[6];
    const float* Wq = (const float*)d_in[7];
    const float* bq = (const float*)d_in[8];
    const float* Wk = (const float*)d_in[9];
    const float* bk = (const float*)d_in[10];
    const float* Wv = (const float*)d_in[11];
    const float* bv = (const float*)d_in[12];
    const float* Wo = (const float*)d_in[13];
    const float* bo = (const float*)d_in[14];
    const float* W1 = (const float*)d_in[15];
    const float* b1 = (const float*)d_in[16];
    const float* W2 = (const float*)d_in[17];
    const float* b2 = (const float*)d_in[18];
    const float* ln1_g = (const float*)d_in[19];
    const float* ln1_b = (const float*)d_in[20];
    const float* ln2_g = (const float*)d_in[21];
    const float* ln2_b = (const float*)d_in[22];
    const float* lnf_g = (const float*)d_in[23];
    const float* lnf_b = (const float*)d_in[24];
    const float* proj_W = (const float*)d_in[25];
    const float* proj_b = (const float*)d_in[26];

    float* dec = (float*)d_out;
    float* means = dec + (size_t)Bn * Pn * Nn;
    float* stdev = means + (size_t)Bn * Nn;

    // ---- workspace carve (~154 MB, proven watermark) ----
    char* p = (char*)d_ws;
    auto alloc = [&](size_t bytes) { char* r = p; p += (bytes + 255) & ~(size_t)255; return r; };
    const size_t RD = (size_t)Bn * Nn * Dn;        // 2,629,632 elements
    const size_t RQ4 = RD * 4;                     // 10,518,528

    bf16* embWb = (bf16*)alloc(262144 * 2);
    bf16* Wqkb = (bf16*)alloc(2 * 524288 * 2);     // per layer: [Wq;Wk] rows, 1024x512
    bf16* Wvb = (bf16*)alloc(2 * 262144 * 2);
    bf16* Wob = (bf16*)alloc(2 * 262144 * 2);
    bf16* W1b = (bf16*)alloc(2 * 1048576 * 2);
    bf16* W2b = (bf16*)alloc(2 * 1048576 * 2);
    bf16* projWb = (bf16*)alloc(49152 * 2);
    float* bqk = (float*)alloc(2048 * 4);

    float* hbuf = (float*)alloc(RD * 4);
    char* regC = alloc(RQ4 * 2);                     // coeffs_b | attn_b
    char* regQ = alloc(RQ4 * 2);                     // QK0b(head) | Smat(head) | recb,x1b | ptmp
    char* regK = alloc(RQ4 * 2);                     // QK0b(tail) | Smat(tail)
    char* regV = alloc(RQ4 * 2);                     // V0b | yb
    char* regT = alloc((size_t)2 * 64 * 512 * KP * 2); // xT_b | QtKt | x1,tmp(x2),hfb
    float* qn2 = (float*)alloc((size_t)2 * 64 * 512 * 4);
    float* kn2 = qn2 + 32768;

    bf16* coeffs_b = (bf16*)regC;
    bf16* attn_b = (bf16*)regC;
    bf16* QK0b = (bf16*)regQ;                        // 20544 x 1024 bf16 = regQ+regK exactly
    bf16* Smat = (bf16*)regQ;                        // 64*512*512 bf16, spans regQ+regK
    bf16* recb = (bf16*)regQ;                        // after Smat dead
    bf16* x1b = (bf16*)(regQ + RD * 2);
    float* ptmp = (float*)regQ;                      // 4 partials x R*Pn fp32
    bf16* V0b = (bf16*)regV;
    bf16* yb = (bf16*)regV;
    bf16* QtKt = (bf16*)regT;                        // Qt | Kt, each 64*512*KP
    bf16* Qt = QtKt;
    bf16* Kt = QtKt + (size_t)64 * 512 * KP;
    bf16* xT_b = (bf16*)regT;                        // dead before QtKt written
    float* x1 = (float*)regT;
    float* tmp = (float*)(regT + RD * 4);            // 2 split-K partials
    bf16* hfb = (bf16*)(regT + RD * 12);

    const int R = Bn * Nn;   // 5136
    const int RQr = R * 4;   // 20544
    const long sbm = (long)4 * Nn * 512;      // per-b stride in V0b/attn
    const long sS = (long)512 * 512;
    const long sTq = (long)512 * KP;          // per-m stride in Qt/Kt
    const long sTb = 4 * sTq;                 // per-b stride in Qt/Kt

    // ---- fused weight conversion (1 launch); Wq/Wk interleave into Wqkb ----
    CvtPack cp;
    int ci = 0;
    auto addcvt = [&](const float* s, bf16* d, int n) { cp.src[ci] = s; cp.dst[ci] = d; cp.cnt[ci] = n; ++ci; };
    addcvt(emb_W, embWb, 262144);
    for (int l = 0; l < 2; ++l) {
        addcvt(Wq + (size_t)l * 262144, Wqkb + (size_t)l * 524288, 262144);
        addcvt(Wk + (size_t)l * 262144, Wqkb + (size_t)l * 524288 + 262144, 262144);
        addcvt(Wv + (size_t)l * 262144, Wvb + (size_t)l * 262144, 262144);
        addcvt(Wo + (size_t)l * 262144, Wob + (size_t)l * 262144, 262144);
        addcvt(W1 + (size_t)l * 1048576, W1b + (size_t)l * 1048576, 1048576);
        addcvt(W2 + (size_t)l * 1048576, W2b + (size_t)l * 1048576, 1048576);
    }
    addcvt(proj_W, projWb, 49152);
    cvt_all_kernel<<<dim3(1048576 / 4 / 256, 14), 256, 0, stream>>>(cp);
    bias_pack_kernel<<<8, 256, 0, stream>>>(bq, bk, bqk);

    stats_kernel<<<dim3((Nn + 255) / 256, Bn), 256, 0, stream>>>(x_enc, means, stdev);
    transpose_norm_kernel<<<dim3(Sn / 32, (Nn + 31) / 32, Bn), dim3(32, 8), 0, stream>>>(
        x_enc, means, stdev, xT_b);

    // h = xT(5136x512) * emb_W^T + emb_b  -> fp32
    mm_kernel<0, 0><<<dim3(4, (R + 127) / 128, 1), 256, 0, stream>>>(
        xT_b, embWb, emb_b, hbuf, R, Dn, Sn, Sn, Sn, Dn, 0, 0, 0, 0, 0, 0, 1);

    for (int l = 0; l < 2; ++l) {
        const float* h0l = h0 + (size_t)l * Nn * 3;
        const float* h1l = h1 + (size_t)l * Nn * 3;
        const float* g0l = g0 + (size_t)l * Nn * 3;
        const float* g1l = g1 + (size_t)l * Nn * 3;

        swt_dec_kernel<<<dim3(Nn, Bn), 128, 0, stream>>>(hbuf, h0l, h1l, coeffs_b);

        // fused QK: rows (b,n,m) x 1024 -> QK0b
        mm_kernel<1, 0><<<dim3(8, (RQr + 127) / 128, 1), 256, 0, stream>>>(
            coeffs_b, Wqkb + (size_t)l * 524288, bqk + (size_t)l * 1024, QK0b,
            RQr, 1024, Dn, Dn, Dn, 1024, 0, 0, 0, 0, 0, 0, 1);
        // V: rows (b,n,m) x 512 -> V0b
        mm_kernel<1, 0><<<dim3(4, (RQr + 127) / 128, 1), 256, 0, stream>>>(
            coeffs_b, Wvb + (size_t)l * 262144, bv + (size_t)l * Dn, V0b,
            RQr, Dn, Dn, Dn, Dn, Dn, 0, 0, 0, 0, 0, 0, 1);

        colsq2_kernel<<<dim3(8, 128), 256, 0, stream>>>(QK0b, qn2);
        tconv2_kernel<<<dim3(16, 11, 128), dim3(32, 8), 0, stream>>>(QK0b, QtKt);

        // dot[bm,l,s] = sum_n Qt[l,n]*Kt[s,n] -> bf16 Smat (QK0b dead now)
        mm_kernel<1, 0><<<dim3(4, 4, 64), 256, 0, stream>>>(
            Qt, Kt, nullptr, Smat, 512, 512, KP, KP, KP, 512,
            sTq, sTb, sTq, sTb, sS, 4 * sS, 4);

        wedge_softmax_kernel<<<dim3(512, 64), 256, 0, stream>>>(Smat, qn2, kn2);

        // attn[b,m,n,l] = sum_s V0b[(b,n,m),s] * Smat[bm,l,s] -> bf16
        mm_kernel<1, 0><<<dim3(4, (Nn + 127) / 128, 64), 256, 0, stream>>>(
            V0b, Smat, nullptr, attn_b, Nn, 512, 512, 2048, 512, 512,
            512, sbm, sS, 4 * sS, (long)Nn * 512, (long)4 * Nn * 512, 4);

        // Smat dead; recb overwrites its head
        swt_rec_kernel<<<dim3(Nn, Bn), 128, 0, stream>>>(attn_b, g0l, g1l, recb);

        // Wo split-K=2 -> tmp partials
        mm_kernel<0, 0><<<dim3(4, (R + 127) / 128, 2), 256, 0, stream>>>(
            recb, Wob + (size_t)l * 262144, bo + (size_t)l * Dn, tmp,
            R, Dn, 256, Dn, Dn, Dn, 256, 0, 256, 0, (long)RD, 0, 2);
        ln_kernel<<<R, 128, 0, stream>>>(hbuf, tmp, tmp + RD, ln1_g + (size_t)l * Dn,
                                         ln1_b + (size_t)l * Dn, x1, x1b);

        // FFN1 (gelu, bf16 out)
        mm_kernel<1, 1><<<dim3(16, (R + 127) / 128, 1), 256, 0, stream>>>(
            x1b, W1b + (size_t)l * 1048576, b1 + (size_t)l * DFn, yb,
            R, DFn, Dn, Dn, Dn, DFn, 0, 0, 0, 0, 0, 0, 1);
        // FFN2 split-K=2 -> tmp partials
        mm_kernel<0, 0><<<dim3(4, (R + 127) / 128, 2), 256, 0, stream>>>(
            yb, W2b + (size_t)l * 1048576, b2 + (size_t)l * Dn, tmp,
            R, Dn, 1024, DFn, DFn, Dn, 1024, 0, 1024, 0, (long)RD, 0, 2);
        ln_kernel<<<R, 128, 0, stream>>>(x1, tmp, tmp + RD, ln2_g + (size_t)l * Dn,
                                         ln2_b + (size_t)l * Dn, hbuf, nullptr);
    }

    ln_kernel<<<R, 128, 0, stream>>>(hbuf, nullptr, nullptr, lnf_g, lnf_b, nullptr, hfb);
    // proj split-K=4 -> ptmp partials
    mm_kernel<0, 0><<<dim3(1, (R + 127) / 128, 4), 256, 0, stream>>>(
        hfb, projWb, proj_b, ptmp, R, Pn, 128, Dn, Dn, Pn,
        128, 0, 128, 0, (long)R * Pn, 0, 4);
    out_scale_kernel<<<(Bn * Pn * Nn + 255) / 256, 256, 0, stream>>>(ptmp, means, stdev, dec);
}